// Round 3
// baseline (3327.950 us; speedup 1.0000x reference)
//
#include <hip/hip_runtime.h>
#include <cstddef>

#define LL 2048
#define TOK 8192   // B*L = 4*2048
#define DM 1024
#define DI 2048
#define NS 16

// ---------- helpers ----------
__device__ __forceinline__ float bf2f(unsigned short u) {
  union { unsigned int i; float f; } v; v.i = ((unsigned int)u) << 16; return v.f;
}
__device__ __forceinline__ float softplus_f(float x) {
  return fmaxf(x, 0.f) + log1pf(__expf(-fabsf(x)));
}
__device__ __forceinline__ float silu_f(float x) {
  return x / (1.f + __expf(-x));
}

// ---------- static scratch ----------
__device__ float g_buf[119881760];

// ---------- dtype detector: bf16 weights have exponent <= ~122; fp32 mantissa
// halves interpreted as bf16 have uniform-random exponents (>140 w.h.p.) ----------
__global__ __launch_bounds__(256) void detect_k(const unsigned short* __restrict__ w,
                                                int* __restrict__ flag) {
  __shared__ int m;
  if (threadIdx.x == 0) m = 0;
  __syncthreads();
  int e = 0;
  for (int i = threadIdx.x; i < 8192; i += 256) {
    int ex = (w[i] >> 7) & 0xFF;
    e = ex > e ? ex : e;
  }
  atomicMax(&m, e);
  __syncthreads();
  if (threadIdx.x == 0) *flag = (m > 140) ? 1 : 0;  // 1 => inputs are fp32
}

// ---------- dual-mode staging: decode bf16 or copy fp32 per flag ----------
__global__ __launch_bounds__(256) void cvt_auto(const void* __restrict__ in,
                                                float* __restrict__ out, int n,
                                                const int* __restrict__ flag) {
  const int f = *flag;
  int i = blockIdx.x * 256 + threadIdx.x;
  const int stride = gridDim.x * 256;
  if (f) {
    const float* p = (const float*)in;
    for (; i < n; i += stride) out[i] = p[i];
  } else {
    const unsigned short* p = (const unsigned short*)in;
    for (; i < n; i += stride) out[i] = bf2f(p[i]);
  }
}

// ---------- fp32 GEMM: C[M,N] = act(A[M,K] @ W[N,K]^T + bias) ----------
// 128x128 tile, BK=8, 256 threads, 8x8 per thread. fp32 output.
template <int ACT>   // ACT: 0 none, 1 silu, 2 softplus+clip
__global__ __launch_bounds__(256) void gemm_k(const float* __restrict__ A,
                                              const float* __restrict__ W,
                                              const float* __restrict__ bias,
                                              float* __restrict__ C,
                                              int M, int N, int K) {
  __shared__ float As[8][132];
  __shared__ float Ws[8][132];
  const int tid = threadIdx.x;
  const int bm0 = blockIdx.y * 128, bn0 = blockIdx.x * 128;
  const int tx = tid & 15, ty = tid >> 4;
  const int lr = tid >> 1, lk = (tid & 1) << 2;
  const float* ag = A + (size_t)(bm0 + lr) * K + lk;
  const float* wg = W + (size_t)(bn0 + lr) * K + lk;
  float acc[8][8];
#pragma unroll
  for (int i = 0; i < 8; ++i)
#pragma unroll
    for (int j = 0; j < 8; ++j) acc[i][j] = 0.f;

  for (int k0 = 0; k0 < K; k0 += 8) {
    const float4 av = *(const float4*)(ag + k0);
    const float4 wv = *(const float4*)(wg + k0);
    __syncthreads();
    As[lk + 0][lr] = av.x; As[lk + 1][lr] = av.y;
    As[lk + 2][lr] = av.z; As[lk + 3][lr] = av.w;
    Ws[lk + 0][lr] = wv.x; Ws[lk + 1][lr] = wv.y;
    Ws[lk + 2][lr] = wv.z; Ws[lk + 3][lr] = wv.w;
    __syncthreads();
#pragma unroll
    for (int kk = 0; kk < 8; ++kk) {
      const float4 a0 = *(const float4*)&As[kk][ty * 8];
      const float4 a1 = *(const float4*)&As[kk][ty * 8 + 4];
      const float4 b0 = *(const float4*)&Ws[kk][tx * 8];
      const float4 b1 = *(const float4*)&Ws[kk][tx * 8 + 4];
      const float a[8] = {a0.x, a0.y, a0.z, a0.w, a1.x, a1.y, a1.z, a1.w};
      const float b[8] = {b0.x, b0.y, b0.z, b0.w, b1.x, b1.y, b1.z, b1.w};
#pragma unroll
      for (int i = 0; i < 8; ++i)
#pragma unroll
        for (int j = 0; j < 8; ++j) acc[i][j] = fmaf(a[i], b[j], acc[i][j]);
    }
  }

#pragma unroll
  for (int i = 0; i < 8; ++i) {
    const int row = bm0 + ty * 8 + i;
    float vv[8];
#pragma unroll
    for (int j = 0; j < 8; ++j) {
      const int col = bn0 + tx * 8 + j;
      float v = acc[i][j];
      if (bias) v += bias[col];
      if (ACT == 1) v = silu_f(v);
      if (ACT == 2) { v = softplus_f(v); v = fminf(fmaxf(v, 1e-4f), 10.f); }
      vv[j] = v;
    }
    const size_t base = (size_t)row * N + bn0 + tx * 8;
    *(float4*)&C[base]     = make_float4(vv[0], vv[1], vv[2], vv[3]);
    *(float4*)&C[base + 4] = make_float4(vv[4], vv[5], vv[6], vv[7]);
  }
}

// ---------- causal depthwise conv(4) + bias + silu ----------
__global__ __launch_bounds__(256) void conv_silu_k(const float* __restrict__ left,
                                                   const float* __restrict__ cw,
                                                   const float* __restrict__ cb,
                                                   float* __restrict__ xc) {
  const int idx = blockIdx.x * 256 + threadIdx.x;  // over TOK*DI
  const int d = idx & (DI - 1);
  const int bt = idx >> 11;
  const int t = bt & (LL - 1);
  const float4 wv = *(const float4*)(cw + (size_t)d * 4);
  float acc = cb[d];
  const size_t base = (size_t)idx;
  if (t >= 3) {
    acc += left[base - 3 * DI] * wv.x + left[base - 2 * DI] * wv.y +
           left[base - DI] * wv.z + left[base] * wv.w;
  } else {
    acc += left[base] * wv.w;
    if (t >= 1) acc += left[base - DI] * wv.z;
    if (t >= 2) acc += left[base - 2 * DI] * wv.y;
  }
  xc[base] = silu_f(acc);
}

// ---------- B/C projection: bc[row][0:16]=xc@W_B^T, [16:32]=xc@W_C^T ----------
__global__ __launch_bounds__(256) void bc_k(const float* __restrict__ xc,
                                            const float* __restrict__ wbc,
                                            float* __restrict__ bc) {
  __shared__ float xs[DI];
  __shared__ float red[8][32];
  const int row = blockIdx.x;
  const float* xr = xc + (size_t)row * DI;
  for (int i = threadIdx.x; i < DI; i += 256) xs[i] = xr[i];
  __syncthreads();
  const int n = threadIdx.x & 31, part = threadIdx.x >> 5;
  const float* wr = wbc + (size_t)n * DI + part * 256;
  const float* xp = xs + part * 256;
  float s = 0.f;
#pragma unroll 4
  for (int k = 0; k < 256; ++k) s = fmaf(xp[k], wr[k], s);
  red[part][n] = s;
  __syncthreads();
  if (part == 0) {
    float t = 0.f;
#pragma unroll
    for (int j = 0; j < 8; ++j) t += red[j][n];
    bc[(size_t)row * 32 + n] = t;
  }
}

// ---------- selective scan (16 lanes per channel, gate fused) ----------
#define ST 32
__global__ __launch_bounds__(256) void scan_k(const float* __restrict__ delta,
                                              const float* __restrict__ xc,
                                              const float* __restrict__ gate,
                                              const float* __restrict__ bc,
                                              const float* __restrict__ A_log,
                                              float* __restrict__ y) {
  __shared__ float ds[ST][16], xs[ST][16], gs[ST][16];
  __shared__ float Bs[ST][16], Cs[ST][16], ys[ST][16];
  const int tid = threadIdx.x;
  const int b = blockIdx.x >> 7;            // 128 blocks per batch
  const int d0 = (blockIdx.x & 127) << 4;   // 16 channels per block
  const int n = tid & 15, ch = tid >> 4;
  const float An = -softplus_f(A_log[n]);
  float h = 0.f;
  const int tt1 = tid >> 4, dd1 = tid & 15;
  const int e2 = tid + 256;
  const int tt2 = e2 >> 4, dd2 = e2 & 15;

  for (int t0 = 0; t0 < LL; t0 += ST) {
    const size_t rowbase = ((size_t)(b * LL + t0)) * DI + d0;
    ds[tt1][dd1] = delta[rowbase + (size_t)tt1 * DI + dd1];
    ds[tt2][dd2] = delta[rowbase + (size_t)tt2 * DI + dd2];
    xs[tt1][dd1] = xc[rowbase + (size_t)tt1 * DI + dd1];
    xs[tt2][dd2] = xc[rowbase + (size_t)tt2 * DI + dd2];
    gs[tt1][dd1] = gate[rowbase + (size_t)tt1 * DI + dd1];
    gs[tt2][dd2] = gate[rowbase + (size_t)tt2 * DI + dd2];
    {
      const int tt = tid >> 3, c4 = (tid & 7) << 2;
      const float4 v = *(const float4*)(bc + ((size_t)(b * LL + t0 + tt)) * 32 + c4);
      const float vv[4] = {v.x, v.y, v.z, v.w};
#pragma unroll
      for (int q = 0; q < 4; ++q) {
        const int c = c4 + q;
        if (c < 16) Bs[tt][c] = vv[q]; else Cs[tt][c - 16] = vv[q];
      }
    }
    __syncthreads();
#pragma unroll 4
    for (int tt = 0; tt < ST; ++tt) {
      const float dlt = ds[tt][ch];
      const float xv = xs[tt][ch];
      const float bn = Bs[tt][n];
      const float cn = Cs[tt][n];
      const float ab = __expf(dlt * An);
      h = fmaf(ab, h, dlt * xv * bn);
      float p = h * cn;
      p += __shfl_xor(p, 1);
      p += __shfl_xor(p, 2);
      p += __shfl_xor(p, 4);
      p += __shfl_xor(p, 8);
      if (n == 0) ys[tt][ch] = p * gs[tt][ch];
    }
    __syncthreads();
    y[rowbase + (size_t)tt1 * DI + dd1] = ys[tt1][dd1];
    y[rowbase + (size_t)tt2 * DI + dd2] = ys[tt2][dd2];
    __syncthreads();
  }
}

// ---------- layernorm over d_inner ----------
__global__ __launch_bounds__(256) void ln_k(const float* __restrict__ y,
                                            const float* __restrict__ gam,
                                            const float* __restrict__ bet,
                                            float* __restrict__ outn) {
  const int row = blockIdx.x;
  const int tid = threadIdx.x;
  const float* yr = y + (size_t)row * DI;
  const float4 v0 = ((const float4*)yr)[tid];
  const float4 v1 = ((const float4*)yr)[tid + 256];
  float s = v0.x + v0.y + v0.z + v0.w + v1.x + v1.y + v1.z + v1.w;
  float q = v0.x * v0.x + v0.y * v0.y + v0.z * v0.z + v0.w * v0.w +
            v1.x * v1.x + v1.y * v1.y + v1.z * v1.z + v1.w * v1.w;
  for (int off = 32; off > 0; off >>= 1) {
    s += __shfl_down(s, off);
    q += __shfl_down(q, off);
  }
  __shared__ float sred[4], qred[4];
  const int wid = tid >> 6;
  if ((tid & 63) == 0) { sred[wid] = s; qred[wid] = q; }
  __syncthreads();
  s = sred[0] + sred[1] + sred[2] + sred[3];
  q = qred[0] + qred[1] + qred[2] + qred[3];
  const float mu = s * (1.f / DI);
  const float rs = rsqrtf(q * (1.f / DI) - mu * mu + 1e-5f);
  float* orow = outn + (size_t)row * DI;
  const int c0 = tid * 4, c1 = (tid + 256) * 4;
  float4 o;
  o.x = (v0.x - mu) * rs * gam[c0 + 0] + bet[c0 + 0];
  o.y = (v0.y - mu) * rs * gam[c0 + 1] + bet[c0 + 1];
  o.z = (v0.z - mu) * rs * gam[c0 + 2] + bet[c0 + 2];
  o.w = (v0.w - mu) * rs * gam[c0 + 3] + bet[c0 + 3];
  ((float4*)orow)[tid] = o;
  o.x = (v1.x - mu) * rs * gam[c1 + 0] + bet[c1 + 0];
  o.y = (v1.y - mu) * rs * gam[c1 + 1] + bet[c1 + 1];
  o.z = (v1.z - mu) * rs * gam[c1 + 2] + bet[c1 + 2];
  o.w = (v1.w - mu) * rs * gam[c1 + 3] + bet[c1 + 3];
  ((float4*)orow)[tid + 256] = o;
}

// ---------- host launch ----------
extern "C" void kernel_launch(void* const* d_in, const int* in_sizes, int n_in,
                              void* d_out, int out_size, void* d_ws, size_t ws_size,
                              hipStream_t stream) {
  const void* x       = d_in[0];
  const void* W_left  = d_in[1];
  const void* conv_w  = d_in[2];
  const void* conv_b  = d_in[3];
  const void* W_delta = d_in[4];
  const void* b_delta = d_in[5];
  const void* W_B     = d_in[6];
  const void* W_C     = d_in[7];
  const void* A_log   = d_in[8];
  const void* W_right = d_in[9];
  const void* ln_g    = d_in[10];
  const void* ln_b    = d_in[11];
  const void* W_out   = d_in[12];

  float* buf = nullptr;
  hipGetSymbolAddress((void**)&buf, HIP_SYMBOL(g_buf));
  float* xf    = buf + 0;
  float* wl    = buf + 8388608;
  float* wr    = buf + 10485760;
  float* wd    = buf + 12582912;
  float* wo    = buf + 16777216;
  float* wbc   = buf + 18874368;
  float* left  = buf + 18939904;
  float* xc    = buf + 35717120;
  float* dlt   = buf + 52494336;
  float* gate  = buf + 69271552;
  float* yv    = buf + 86048768;
  float* nrm   = buf + 102825984;
  float* bc    = buf + 119603200;
  float* cwf   = buf + 119865344;
  float* cbf   = buf + 119873536;
  float* bdf   = buf + 119875584;
  float* alf   = buf + 119877632;
  float* lgf   = buf + 119877648;
  float* lbf   = buf + 119879696;
  int*   flag  = (int*)(buf + 119881744);

  // detect input dtype from W_left's bit patterns
  detect_k<<<1, 256, 0, stream>>>((const unsigned short*)W_left, flag);

  // stage all inputs to fp32
  cvt_auto<<<2048, 256, 0, stream>>>(x, xf, TOK * DM, flag);
  cvt_auto<<<1024, 256, 0, stream>>>(W_left, wl, DI * DM, flag);
  cvt_auto<<<1024, 256, 0, stream>>>(W_right, wr, DI * DM, flag);
  cvt_auto<<<2048, 256, 0, stream>>>(W_delta, wd, DI * DI, flag);
  cvt_auto<<<1024, 256, 0, stream>>>(W_out, wo, DM * DI, flag);
  cvt_auto<<<64, 256, 0, stream>>>(W_B, wbc, NS * DI, flag);
  cvt_auto<<<64, 256, 0, stream>>>(W_C, wbc + NS * DI, NS * DI, flag);
  cvt_auto<<<8, 256, 0, stream>>>(conv_w, cwf, DI * 4, flag);
  cvt_auto<<<2, 256, 0, stream>>>(conv_b, cbf, DI, flag);
  cvt_auto<<<2, 256, 0, stream>>>(b_delta, bdf, DI, flag);
  cvt_auto<<<1, 256, 0, stream>>>(A_log, alf, NS, flag);
  cvt_auto<<<2, 256, 0, stream>>>(ln_g, lgf, DI, flag);
  cvt_auto<<<2, 256, 0, stream>>>(ln_b, lbf, DI, flag);

  // left = x @ W_left^T
  gemm_k<0><<<dim3(DI / 128, TOK / 128), 256, 0, stream>>>(xf, wl, nullptr, left, TOK, DI, DM);
  // xc = silu(causal_conv(left))
  conv_silu_k<<<TOK * DI / 256, 256, 0, stream>>>(left, cwf, cbf, xc);
  // gate = silu(x @ W_right^T)
  gemm_k<1><<<dim3(DI / 128, TOK / 128), 256, 0, stream>>>(xf, wr, nullptr, gate, TOK, DI, DM);
  // delta = clip(softplus(xc @ W_delta^T + b_delta))
  gemm_k<2><<<dim3(DI / 128, TOK / 128), 256, 0, stream>>>(xc, wd, bdf, dlt, TOK, DI, DI);
  // B/C projections
  bc_k<<<TOK, 256, 0, stream>>>(xc, wbc, bc);
  // selective scan with fused gate
  scan_k<<<512, 256, 0, stream>>>(dlt, xc, gate, bc, alf, yv);
  // layernorm
  ln_k<<<TOK, 256, 0, stream>>>(yv, lgf, lbf, nrm);
  // out = nrm @ W_out^T  (fp32 store to d_out)
  gemm_k<0><<<dim3(DM / 128, TOK / 128), 256, 0, stream>>>(nrm, wo, nullptr, (float*)d_out, TOK, DM, DI);
}

// Round 5
// 1821.994 us; speedup vs baseline: 1.8265x; 1.8265x over previous
//
#include <hip/hip_runtime.h>
#include <cstddef>

#define LL 2048
#define TOK 8192   // B*L = 4*2048
#define DM 1024
#define DI 2048
#define NS 16

typedef _Float16 half_t;
typedef __attribute__((ext_vector_type(8))) _Float16 f16x8;
typedef __attribute__((ext_vector_type(4))) _Float16 f16x4;
typedef __attribute__((ext_vector_type(4))) float f32x4;

// ---------- helpers ----------
__device__ __forceinline__ float softplus_f(float x) {
  return fmaxf(x, 0.f) + log1pf(__expf(-fabsf(x)));
}
__device__ __forceinline__ float silu_f(float x) {
  return x / (1.f + __expf(-x));
}
__device__ __forceinline__ void gload_lds16(const void* g, void* l) {
  __builtin_amdgcn_global_load_lds((const __attribute__((address_space(1))) void*)g,
                                   (__attribute__((address_space(3))) void*)l, 16, 0, 0);
}

// ---------- static scratch (float units) ----------
//  xh    @ 0            (4,194,304)   x as fp16
//  wlh   @ 4,194,304    (1,048,576)
//  wrh   @ 5,242,880    (1,048,576)
//  wdh   @ 6,291,456    (2,097,152)   W_delta hi
//  wdl   @ 8,388,608    (2,097,152)   W_delta lo
//  woh   @ 10,485,760   (1,048,576)
//  left  @ 11,534,336   (16,777,216)
//  xc    @ 28,311,552   (16,777,216)
//  xch   @ 45,088,768   (8,388,608)   xc hi fp16
//  xcl   @ 53,477,376   (8,388,608)   xc lo fp16
//  dlt   @ 61,865,984   (16,777,216)
//  gate  @ 78,643,200   (16,777,216)
//  y     @ 95,420,416   (16,777,216)
//  nrmh  @ 112,197,632  (8,388,608)   LN out fp16
//  bc    @ 120,586,240  (262,144)
__device__ float g_buf[120848384];

// ---------- fp32 -> fp16 staging ----------
__global__ __launch_bounds__(256) void f2h_k(const float* __restrict__ in,
                                             half_t* __restrict__ out, int n4) {
  const int i = blockIdx.x * 256 + threadIdx.x;
  if (i >= n4) return;
  const float4 v = ((const float4*)in)[i];
  f16x4 o;
  o[0] = (half_t)v.x; o[1] = (half_t)v.y; o[2] = (half_t)v.z; o[3] = (half_t)v.w;
  ((f16x4*)out)[i] = o;
}

// ---------- fp32 -> (hi, lo) fp16 split staging ----------
__global__ __launch_bounds__(256) void f2h2_k(const float* __restrict__ in,
                                              half_t* __restrict__ hi,
                                              half_t* __restrict__ lo, int n4) {
  const int i = blockIdx.x * 256 + threadIdx.x;
  if (i >= n4) return;
  const float4 v = ((const float4*)in)[i];
  f16x4 h, l;
  h[0] = (half_t)v.x; h[1] = (half_t)v.y; h[2] = (half_t)v.z; h[3] = (half_t)v.w;
  l[0] = (half_t)(v.x - (float)h[0]);
  l[1] = (half_t)(v.y - (float)h[1]);
  l[2] = (half_t)(v.z - (float)h[2]);
  l[3] = (half_t)(v.w - (float)h[3]);
  ((f16x4*)hi)[i] = h;
  ((f16x4*)lo)[i] = l;
}

// ---------- fp16 MFMA GEMM: C[M,N] = act(A[M,K] @ W[N,K]^T + bias), fp32 out --
// 128x128 tile, BK=32, 256 threads (4 waves, 64x64 each), 16x16x32 MFMA.
template <int ACT>   // 0 none, 1 silu
__global__ __launch_bounds__(256) void gemm_mfma(const half_t* __restrict__ A,
                                                 const half_t* __restrict__ W,
                                                 const float* __restrict__ bias,
                                                 float* __restrict__ C,
                                                 int M, int N, int K) {
  __shared__ half_t lA[4096];   // 8 KB
  __shared__ half_t lB[4096];   // 8 KB
  const int tid = threadIdx.x;
  const int bm0 = blockIdx.y * 128, bn0 = blockIdx.x * 128;
  const int lane = tid & 63, wave = tid >> 6;
  const int q = lane >> 4, mr = lane & 15;
  const int wm = (wave >> 1) * 64, wn = (wave & 1) * 64;
  const int flat0 = tid, flat1 = tid + 256;
  const int kc0 = flat0 >> 7, r0 = flat0 & 127;
  const int kc1 = flat1 >> 7, r1 = flat1 & 127;

  f32x4 acc[4][4];
#pragma unroll
  for (int i = 0; i < 4; ++i)
#pragma unroll
    for (int j = 0; j < 4; ++j) acc[i][j] = (f32x4){0.f, 0.f, 0.f, 0.f};

  for (int k0 = 0; k0 < K; k0 += 32) {
    gload_lds16(A + (size_t)(bm0 + r0) * K + k0 + kc0 * 8, lA + (size_t)flat0 * 8);
    gload_lds16(A + (size_t)(bm0 + r1) * K + k0 + kc1 * 8, lA + (size_t)flat1 * 8);
    gload_lds16(W + (size_t)(bn0 + r0) * K + k0 + kc0 * 8, lB + (size_t)flat0 * 8);
    gload_lds16(W + (size_t)(bn0 + r1) * K + k0 + kc1 * 8, lB + (size_t)flat1 * 8);
    __syncthreads();
    f16x8 af[4], bg[4];
#pragma unroll
    for (int t = 0; t < 4; ++t) {
      af[t] = *(const f16x8*)(lA + ((q << 10) + ((wm + t * 16 + mr) << 3)));
      bg[t] = *(const f16x8*)(lB + ((q << 10) + ((wn + t * 16 + mr) << 3)));
    }
#pragma unroll
    for (int i = 0; i < 4; ++i)
#pragma unroll
      for (int j = 0; j < 4; ++j)
        acc[i][j] = __builtin_amdgcn_mfma_f32_16x16x32_f16(af[i], bg[j], acc[i][j], 0, 0, 0);
    __syncthreads();
  }

#pragma unroll
  for (int i = 0; i < 4; ++i) {
#pragma unroll
    for (int j = 0; j < 4; ++j) {
      const int col = bn0 + wn + j * 16 + mr;
      const float bv = bias ? bias[col] : 0.f;
#pragma unroll
      for (int r = 0; r < 4; ++r) {
        const int row = bm0 + wm + i * 16 + q * 4 + r;
        float v = acc[i][j][r] + bv;
        if (ACT == 1) v = silu_f(v);
        C[(size_t)row * N + col] = v;
      }
    }
  }
}

// ---------- split-fp16 MFMA GEMM (effective ~fp32): delta projection ----------
// acc += Ah*Wh + Ah*Wl + Al*Wh;  epilogue: clip(softplus(. + bias))
__global__ __launch_bounds__(256) void gemm_mfma_split(const half_t* __restrict__ Ah,
                                                       const half_t* __restrict__ Al,
                                                       const half_t* __restrict__ Wh,
                                                       const half_t* __restrict__ Wl,
                                                       const float* __restrict__ bias,
                                                       float* __restrict__ C,
                                                       int M, int N, int K) {
  __shared__ half_t lAh[4096], lAl[4096], lBh[4096], lBl[4096];  // 32 KB
  const int tid = threadIdx.x;
  const int bm0 = blockIdx.y * 128, bn0 = blockIdx.x * 128;
  const int lane = tid & 63, wave = tid >> 6;
  const int q = lane >> 4, mr = lane & 15;
  const int wm = (wave >> 1) * 64, wn = (wave & 1) * 64;
  const int flat0 = tid, flat1 = tid + 256;
  const int kc0 = flat0 >> 7, r0 = flat0 & 127;
  const int kc1 = flat1 >> 7, r1 = flat1 & 127;

  f32x4 acc[4][4];
#pragma unroll
  for (int i = 0; i < 4; ++i)
#pragma unroll
    for (int j = 0; j < 4; ++j) acc[i][j] = (f32x4){0.f, 0.f, 0.f, 0.f};

  for (int k0 = 0; k0 < K; k0 += 32) {
    const size_t ga0 = (size_t)(bm0 + r0) * K + k0 + kc0 * 8;
    const size_t ga1 = (size_t)(bm0 + r1) * K + k0 + kc1 * 8;
    const size_t gb0 = (size_t)(bn0 + r0) * K + k0 + kc0 * 8;
    const size_t gb1 = (size_t)(bn0 + r1) * K + k0 + kc1 * 8;
    gload_lds16(Ah + ga0, lAh + (size_t)flat0 * 8);
    gload_lds16(Ah + ga1, lAh + (size_t)flat1 * 8);
    gload_lds16(Al + ga0, lAl + (size_t)flat0 * 8);
    gload_lds16(Al + ga1, lAl + (size_t)flat1 * 8);
    gload_lds16(Wh + gb0, lBh + (size_t)flat0 * 8);
    gload_lds16(Wh + gb1, lBh + (size_t)flat1 * 8);
    gload_lds16(Wl + gb0, lBl + (size_t)flat0 * 8);
    gload_lds16(Wl + gb1, lBl + (size_t)flat1 * 8);
    __syncthreads();
#pragma unroll
    for (int i = 0; i < 4; ++i) {
      const int ao = (q << 10) + ((wm + i * 16 + mr) << 3);
      const f16x8 ah = *(const f16x8*)(lAh + ao);
      const f16x8 al = *(const f16x8*)(lAl + ao);
#pragma unroll
      for (int j = 0; j < 4; ++j) {
        const int bo = (q << 10) + ((wn + j * 16 + mr) << 3);
        const f16x8 bh = *(const f16x8*)(lBh + bo);
        const f16x8 bl = *(const f16x8*)(lBl + bo);
        acc[i][j] = __builtin_amdgcn_mfma_f32_16x16x32_f16(ah, bh, acc[i][j], 0, 0, 0);
        acc[i][j] = __builtin_amdgcn_mfma_f32_16x16x32_f16(ah, bl, acc[i][j], 0, 0, 0);
        acc[i][j] = __builtin_amdgcn_mfma_f32_16x16x32_f16(al, bh, acc[i][j], 0, 0, 0);
      }
    }
    __syncthreads();
  }

#pragma unroll
  for (int i = 0; i < 4; ++i) {
#pragma unroll
    for (int j = 0; j < 4; ++j) {
      const int col = bn0 + wn + j * 16 + mr;
      const float bv = bias[col];
#pragma unroll
      for (int r = 0; r < 4; ++r) {
        const int row = bm0 + wm + i * 16 + q * 4 + r;
        float v = softplus_f(acc[i][j][r] + bv);
        v = fminf(fmaxf(v, 1e-4f), 10.f);
        C[(size_t)row * N + col] = v;
      }
    }
  }
}

// ---------- causal depthwise conv(4) + bias + silu (fp32 + split-fp16 out) ----
__global__ __launch_bounds__(256) void conv_silu_k(const float* __restrict__ left,
                                                   const float* __restrict__ cw,
                                                   const float* __restrict__ cb,
                                                   float* __restrict__ xc,
                                                   half_t* __restrict__ xch,
                                                   half_t* __restrict__ xcl) {
  const int idx = blockIdx.x * 256 + threadIdx.x;  // over TOK*DI
  const int d = idx & (DI - 1);
  const int bt = idx >> 11;
  const int t = bt & (LL - 1);
  const float4 wv = *(const float4*)(cw + (size_t)d * 4);
  float acc = cb[d];
  const size_t base = (size_t)idx;
  if (t >= 3) {
    acc += left[base - 3 * DI] * wv.x + left[base - 2 * DI] * wv.y +
           left[base - DI] * wv.z + left[base] * wv.w;
  } else {
    acc += left[base] * wv.w;
    if (t >= 1) acc += left[base - DI] * wv.z;
    if (t >= 2) acc += left[base - 2 * DI] * wv.y;
  }
  const float v = silu_f(acc);
  xc[base] = v;
  const half_t h = (half_t)v;
  xch[base] = h;
  xcl[base] = (half_t)(v - (float)h);
}

// ---------- B/C projection: bc[row][0:16]=xc@W_B^T, [16:32]=xc@W_C^T ----------
__global__ __launch_bounds__(256) void bc_k(const float* __restrict__ xc,
                                            const float* __restrict__ wB,
                                            const float* __restrict__ wC,
                                            float* __restrict__ bc) {
  __shared__ float xs[DI];
  __shared__ float red[8][32];
  const int row = blockIdx.x;
  const float* xr = xc + (size_t)row * DI;
  for (int i = threadIdx.x; i < DI; i += 256) xs[i] = xr[i];
  __syncthreads();
  const int n = threadIdx.x & 31, part = threadIdx.x >> 5;
  const float* wr = (n < 16 ? wB + (size_t)n * DI : wC + (size_t)(n - 16) * DI) + part * 256;
  const float* xp = xs + part * 256;
  float s = 0.f;
#pragma unroll 4
  for (int k = 0; k < 256; ++k) s = fmaf(xp[k], wr[k], s);
  red[part][n] = s;
  __syncthreads();
  if (part == 0) {
    float t = 0.f;
#pragma unroll
    for (int j = 0; j < 8; ++j) t += red[j][n];
    bc[(size_t)row * 32 + n] = t;
  }
}

// ---------- selective scan (16 lanes per channel, gate fused) ----------
#define ST 32
__global__ __launch_bounds__(256) void scan_k(const float* __restrict__ delta,
                                              const float* __restrict__ xc,
                                              const float* __restrict__ gate,
                                              const float* __restrict__ bc,
                                              const float* __restrict__ A_log,
                                              float* __restrict__ y) {
  __shared__ float ds[ST][16], xs[ST][16], gs[ST][16];
  __shared__ float Bs[ST][16], Cs[ST][16], ys[ST][16];
  const int tid = threadIdx.x;
  const int b = blockIdx.x >> 7;
  const int d0 = (blockIdx.x & 127) << 4;
  const int n = tid & 15, ch = tid >> 4;
  const float An = -softplus_f(A_log[n]);
  float h = 0.f;
  const int tt1 = tid >> 4, dd1 = tid & 15;
  const int e2 = tid + 256;
  const int tt2 = e2 >> 4, dd2 = e2 & 15;

  for (int t0 = 0; t0 < LL; t0 += ST) {
    const size_t rowbase = ((size_t)(b * LL + t0)) * DI + d0;
    ds[tt1][dd1] = delta[rowbase + (size_t)tt1 * DI + dd1];
    ds[tt2][dd2] = delta[rowbase + (size_t)tt2 * DI + dd2];
    xs[tt1][dd1] = xc[rowbase + (size_t)tt1 * DI + dd1];
    xs[tt2][dd2] = xc[rowbase + (size_t)tt2 * DI + dd2];
    gs[tt1][dd1] = gate[rowbase + (size_t)tt1 * DI + dd1];
    gs[tt2][dd2] = gate[rowbase + (size_t)tt2 * DI + dd2];
    {
      const int tt = tid >> 3, c4 = (tid & 7) << 2;
      const float4 v = *(const float4*)(bc + ((size_t)(b * LL + t0 + tt)) * 32 + c4);
      const float vv[4] = {v.x, v.y, v.z, v.w};
#pragma unroll
      for (int qq = 0; qq < 4; ++qq) {
        const int c = c4 + qq;
        if (c < 16) Bs[tt][c] = vv[qq]; else Cs[tt][c - 16] = vv[qq];
      }
    }
    __syncthreads();
#pragma unroll 4
    for (int tt = 0; tt < ST; ++tt) {
      const float dlt = ds[tt][ch];
      const float xv = xs[tt][ch];
      const float bn = Bs[tt][n];
      const float cn = Cs[tt][n];
      const float ab = __expf(dlt * An);
      h = fmaf(ab, h, dlt * xv * bn);
      float p = h * cn;
      p += __shfl_xor(p, 1);
      p += __shfl_xor(p, 2);
      p += __shfl_xor(p, 4);
      p += __shfl_xor(p, 8);
      if (n == 0) ys[tt][ch] = p * gs[tt][ch];
    }
    __syncthreads();
    y[rowbase + (size_t)tt1 * DI + dd1] = ys[tt1][dd1];
    y[rowbase + (size_t)tt2 * DI + dd2] = ys[tt2][dd2];
    __syncthreads();
  }
}

// ---------- layernorm over d_inner (fp16 out for MFMA consumer) ----------
__global__ __launch_bounds__(256) void ln_k(const float* __restrict__ y,
                                            const float* __restrict__ gam,
                                            const float* __restrict__ bet,
                                            half_t* __restrict__ outn) {
  const int row = blockIdx.x;
  const int tid = threadIdx.x;
  const float* yr = y + (size_t)row * DI;
  const float4 v0 = ((const float4*)yr)[tid];
  const float4 v1 = ((const float4*)yr)[tid + 256];
  float s = v0.x + v0.y + v0.z + v0.w + v1.x + v1.y + v1.z + v1.w;
  float q = v0.x * v0.x + v0.y * v0.y + v0.z * v0.z + v0.w * v0.w +
            v1.x * v1.x + v1.y * v1.y + v1.z * v1.z + v1.w * v1.w;
  for (int off = 32; off > 0; off >>= 1) {
    s += __shfl_down(s, off);
    q += __shfl_down(q, off);
  }
  __shared__ float sred[4], qred[4];
  const int wid = tid >> 6;
  if ((tid & 63) == 0) { sred[wid] = s; qred[wid] = q; }
  __syncthreads();
  s = sred[0] + sred[1] + sred[2] + sred[3];
  q = qred[0] + qred[1] + qred[2] + qred[3];
  const float mu = s * (1.f / DI);
  const float rs = rsqrtf(q * (1.f / DI) - mu * mu + 1e-5f);
  half_t* orow = outn + (size_t)row * DI;
  const int c0 = tid * 4, c1 = (tid + 256) * 4;
  f16x4 o;
  o[0] = (half_t)((v0.x - mu) * rs * gam[c0 + 0] + bet[c0 + 0]);
  o[1] = (half_t)((v0.y - mu) * rs * gam[c0 + 1] + bet[c0 + 1]);
  o[2] = (half_t)((v0.z - mu) * rs * gam[c0 + 2] + bet[c0 + 2]);
  o[3] = (half_t)((v0.w - mu) * rs * gam[c0 + 3] + bet[c0 + 3]);
  ((f16x4*)orow)[tid] = o;
  o[0] = (half_t)((v1.x - mu) * rs * gam[c1 + 0] + bet[c1 + 0]);
  o[1] = (half_t)((v1.y - mu) * rs * gam[c1 + 1] + bet[c1 + 1]);
  o[2] = (half_t)((v1.z - mu) * rs * gam[c1 + 2] + bet[c1 + 2]);
  o[3] = (half_t)((v1.w - mu) * rs * gam[c1 + 3] + bet[c1 + 3]);
  ((f16x4*)orow)[tid + 256] = o;
}

// ---------- host launch ----------
extern "C" void kernel_launch(void* const* d_in, const int* in_sizes, int n_in,
                              void* d_out, int out_size, void* d_ws, size_t ws_size,
                              hipStream_t stream) {
  const float* x       = (const float*)d_in[0];
  const float* W_left  = (const float*)d_in[1];
  const float* conv_w  = (const float*)d_in[2];
  const float* conv_b  = (const float*)d_in[3];
  const float* W_delta = (const float*)d_in[4];
  const float* b_delta = (const float*)d_in[5];
  const float* W_B     = (const float*)d_in[6];
  const float* W_C     = (const float*)d_in[7];
  const float* A_log   = (const float*)d_in[8];
  const float* W_right = (const float*)d_in[9];
  const float* ln_g    = (const float*)d_in[10];
  const float* ln_b    = (const float*)d_in[11];
  const float* W_out   = (const float*)d_in[12];

  float* buf = nullptr;
  hipGetSymbolAddress((void**)&buf, HIP_SYMBOL(g_buf));
  half_t* xh   = (half_t*)(buf + 0);
  half_t* wlh  = (half_t*)(buf + 4194304);
  half_t* wrh  = (half_t*)(buf + 5242880);
  half_t* wdh  = (half_t*)(buf + 6291456);
  half_t* wdl  = (half_t*)(buf + 8388608);
  half_t* woh  = (half_t*)(buf + 10485760);
  float* left  = buf + 11534336;
  float* xc    = buf + 28311552;
  half_t* xch  = (half_t*)(buf + 45088768);
  half_t* xcl  = (half_t*)(buf + 53477376);
  float* dlt   = buf + 61865984;
  float* gate  = buf + 78643200;
  float* yv    = buf + 95420416;
  half_t* nrmh = (half_t*)(buf + 112197632);
  float* bc    = buf + 120586240;

  // fp32 -> fp16 staging
  f2h_k<<<8192, 256, 0, stream>>>(x, xh, TOK * DM / 4);
  f2h_k<<<2048, 256, 0, stream>>>(W_left, wlh, DI * DM / 4);
  f2h_k<<<2048, 256, 0, stream>>>(W_right, wrh, DI * DM / 4);
  f2h_k<<<2048, 256, 0, stream>>>(W_out, woh, DM * DI / 4);
  f2h2_k<<<4096, 256, 0, stream>>>(W_delta, wdh, wdl, DI * DI / 4);

  // left = x @ W_left^T
  gemm_mfma<0><<<dim3(DI / 128, TOK / 128), 256, 0, stream>>>(xh, wlh, nullptr, left, TOK, DI, DM);
  // xc = silu(causal_conv(left))  (fp32 + hi/lo fp16)
  conv_silu_k<<<TOK * DI / 256, 256, 0, stream>>>(left, conv_w, conv_b, xc, xch, xcl);
  // gate = silu(x @ W_right^T)
  gemm_mfma<1><<<dim3(DI / 128, TOK / 128), 256, 0, stream>>>(xh, wrh, nullptr, gate, TOK, DI, DM);
  // delta = clip(softplus(xc @ W_delta^T + b_delta))  [split fp16 ~= fp32]
  gemm_mfma_split<<<dim3(DI / 128, TOK / 128), 256, 0, stream>>>(xch, xcl, wdh, wdl, b_delta, dlt, TOK, DI, DI);
  // B/C projections (fp32, weights direct from d_in)
  bc_k<<<TOK, 256, 0, stream>>>(xc, W_B, W_C, bc);
  // selective scan with fused gate
  scan_k<<<512, 256, 0, stream>>>(dlt, xc, gate, bc, A_log, yv);
  // layernorm -> fp16
  ln_k<<<TOK, 256, 0, stream>>>(yv, ln_g, ln_b, nrmh);
  // out = nrm @ W_out^T  (fp32 store to d_out)
  gemm_mfma<0><<<dim3(DM / 128, TOK / 128), 256, 0, stream>>>(nrmh, woh, nullptr, (float*)d_out, TOK, DM, DI);
}

// Round 6
// 1512.046 us; speedup vs baseline: 2.2010x; 1.2050x over previous
//
#include <hip/hip_runtime.h>
#include <cstddef>

#define LL 2048
#define TOK 8192   // B*L = 4*2048
#define DM 1024
#define DI 2048
#define NS 16

typedef _Float16 half_t;
typedef __attribute__((ext_vector_type(8))) _Float16 f16x8;
typedef __attribute__((ext_vector_type(4))) _Float16 f16x4;
typedef __attribute__((ext_vector_type(4))) float f32x4;

// ---------- helpers ----------
__device__ __forceinline__ float softplus_f(float x) {
  return fmaxf(x, 0.f) + log1pf(__expf(-fabsf(x)));
}
__device__ __forceinline__ float silu_f(float x) {
  return x / (1.f + __expf(-x));
}
__device__ __forceinline__ void gload_lds16(const void* g, void* l) {
  __builtin_amdgcn_global_load_lds((const __attribute__((address_space(1))) void*)g,
                                   (__attribute__((address_space(3))) void*)l, 16, 0, 0);
}
// DPP row_shr add: after ctrl 0x111,0x112,0x114,0x118 lane15 of each row16 holds the row sum
#define DPP_ADD(v, ctrl) \
  ((v) + __int_as_float(__builtin_amdgcn_update_dpp(0, __float_as_int(v), (ctrl), 0xf, 0xf, true)))

// ---------- static scratch (float units) ----------
//  xh    @ 0            (4,194,304)   x as fp16
//  wlh   @ 4,194,304    (1,048,576)
//  wrh   @ 5,242,880    (1,048,576)
//  wdh   @ 6,291,456    (2,097,152)   W_delta hi
//  wdl   @ 8,388,608    (2,097,152)   W_delta lo
//  woh   @ 10,485,760   (1,048,576)
//  left  @ 11,534,336   (16,777,216)
//  xc    @ 28,311,552   (16,777,216)
//  xch   @ 45,088,768   (8,388,608)   xc hi fp16
//  xcl   @ 53,477,376   (8,388,608)   xc lo fp16
//  dlt   @ 61,865,984   (16,777,216)
//  gate  @ 78,643,200   (16,777,216)
//  y     @ 95,420,416   (16,777,216)
//  nrmh  @ 112,197,632  (8,388,608)   LN out fp16
//  bc    @ 120,586,240  (262,144)     packed: [row][2n]=B_n, [2n+1]=C_n
__device__ float g_buf[120848384];

// ---------- fp32 -> fp16 staging ----------
__global__ __launch_bounds__(256) void f2h_k(const float* __restrict__ in,
                                             half_t* __restrict__ out, int n4) {
  const int i = blockIdx.x * 256 + threadIdx.x;
  if (i >= n4) return;
  const float4 v = ((const float4*)in)[i];
  f16x4 o;
  o[0] = (half_t)v.x; o[1] = (half_t)v.y; o[2] = (half_t)v.z; o[3] = (half_t)v.w;
  ((f16x4*)out)[i] = o;
}

// ---------- fp32 -> (hi, lo) fp16 split staging ----------
__global__ __launch_bounds__(256) void f2h2_k(const float* __restrict__ in,
                                              half_t* __restrict__ hi,
                                              half_t* __restrict__ lo, int n4) {
  const int i = blockIdx.x * 256 + threadIdx.x;
  if (i >= n4) return;
  const float4 v = ((const float4*)in)[i];
  f16x4 h, l;
  h[0] = (half_t)v.x; h[1] = (half_t)v.y; h[2] = (half_t)v.z; h[3] = (half_t)v.w;
  l[0] = (half_t)(v.x - (float)h[0]);
  l[1] = (half_t)(v.y - (float)h[1]);
  l[2] = (half_t)(v.z - (float)h[2]);
  l[3] = (half_t)(v.w - (float)h[3]);
  ((f16x4*)hi)[i] = h;
  ((f16x4*)lo)[i] = l;
}

// ---------- fp16 MFMA GEMM: C[M,N] = act(A[M,K] @ W[N,K]^T + bias), fp32 out --
template <int ACT>   // 0 none, 1 silu
__global__ __launch_bounds__(256) void gemm_mfma(const half_t* __restrict__ A,
                                                 const half_t* __restrict__ W,
                                                 const float* __restrict__ bias,
                                                 float* __restrict__ C,
                                                 int M, int N, int K) {
  __shared__ half_t lA[4096];   // 8 KB
  __shared__ half_t lB[4096];   // 8 KB
  const int tid = threadIdx.x;
  const int bm0 = blockIdx.y * 128, bn0 = blockIdx.x * 128;
  const int lane = tid & 63, wave = tid >> 6;
  const int q = lane >> 4, mr = lane & 15;
  const int wm = (wave >> 1) * 64, wn = (wave & 1) * 64;
  const int flat0 = tid, flat1 = tid + 256;
  const int kc0 = flat0 >> 7, r0 = flat0 & 127;
  const int kc1 = flat1 >> 7, r1 = flat1 & 127;

  f32x4 acc[4][4];
#pragma unroll
  for (int i = 0; i < 4; ++i)
#pragma unroll
    for (int j = 0; j < 4; ++j) acc[i][j] = (f32x4){0.f, 0.f, 0.f, 0.f};

  for (int k0 = 0; k0 < K; k0 += 32) {
    gload_lds16(A + (size_t)(bm0 + r0) * K + k0 + kc0 * 8, lA + (size_t)flat0 * 8);
    gload_lds16(A + (size_t)(bm0 + r1) * K + k0 + kc1 * 8, lA + (size_t)flat1 * 8);
    gload_lds16(W + (size_t)(bn0 + r0) * K + k0 + kc0 * 8, lB + (size_t)flat0 * 8);
    gload_lds16(W + (size_t)(bn0 + r1) * K + k0 + kc1 * 8, lB + (size_t)flat1 * 8);
    __syncthreads();
    f16x8 af[4], bg[4];
#pragma unroll
    for (int t = 0; t < 4; ++t) {
      af[t] = *(const f16x8*)(lA + ((q << 10) + ((wm + t * 16 + mr) << 3)));
      bg[t] = *(const f16x8*)(lB + ((q << 10) + ((wn + t * 16 + mr) << 3)));
    }
#pragma unroll
    for (int i = 0; i < 4; ++i)
#pragma unroll
      for (int j = 0; j < 4; ++j)
        acc[i][j] = __builtin_amdgcn_mfma_f32_16x16x32_f16(af[i], bg[j], acc[i][j], 0, 0, 0);
    __syncthreads();
  }

#pragma unroll
  for (int i = 0; i < 4; ++i) {
#pragma unroll
    for (int j = 0; j < 4; ++j) {
      const int col = bn0 + wn + j * 16 + mr;
      const float bv = bias ? bias[col] : 0.f;
#pragma unroll
      for (int r = 0; r < 4; ++r) {
        const int row = bm0 + wm + i * 16 + q * 4 + r;
        float v = acc[i][j][r] + bv;
        if (ACT == 1) v = silu_f(v);
        C[(size_t)row * N + col] = v;
      }
    }
  }
}

// ---------- split-fp16 MFMA GEMM (effective ~fp32): delta projection ----------
__global__ __launch_bounds__(256) void gemm_mfma_split(const half_t* __restrict__ Ah,
                                                       const half_t* __restrict__ Al,
                                                       const half_t* __restrict__ Wh,
                                                       const half_t* __restrict__ Wl,
                                                       const float* __restrict__ bias,
                                                       float* __restrict__ C,
                                                       int M, int N, int K) {
  __shared__ half_t lAh[4096], lAl[4096], lBh[4096], lBl[4096];  // 32 KB
  const int tid = threadIdx.x;
  const int bm0 = blockIdx.y * 128, bn0 = blockIdx.x * 128;
  const int lane = tid & 63, wave = tid >> 6;
  const int q = lane >> 4, mr = lane & 15;
  const int wm = (wave >> 1) * 64, wn = (wave & 1) * 64;
  const int flat0 = tid, flat1 = tid + 256;
  const int kc0 = flat0 >> 7, r0 = flat0 & 127;
  const int kc1 = flat1 >> 7, r1 = flat1 & 127;

  f32x4 acc[4][4];
#pragma unroll
  for (int i = 0; i < 4; ++i)
#pragma unroll
    for (int j = 0; j < 4; ++j) acc[i][j] = (f32x4){0.f, 0.f, 0.f, 0.f};

  for (int k0 = 0; k0 < K; k0 += 32) {
    const size_t ga0 = (size_t)(bm0 + r0) * K + k0 + kc0 * 8;
    const size_t ga1 = (size_t)(bm0 + r1) * K + k0 + kc1 * 8;
    const size_t gb0 = (size_t)(bn0 + r0) * K + k0 + kc0 * 8;
    const size_t gb1 = (size_t)(bn0 + r1) * K + k0 + kc1 * 8;
    gload_lds16(Ah + ga0, lAh + (size_t)flat0 * 8);
    gload_lds16(Ah + ga1, lAh + (size_t)flat1 * 8);
    gload_lds16(Al + ga0, lAl + (size_t)flat0 * 8);
    gload_lds16(Al + ga1, lAl + (size_t)flat1 * 8);
    gload_lds16(Wh + gb0, lBh + (size_t)flat0 * 8);
    gload_lds16(Wh + gb1, lBh + (size_t)flat1 * 8);
    gload_lds16(Wl + gb0, lBl + (size_t)flat0 * 8);
    gload_lds16(Wl + gb1, lBl + (size_t)flat1 * 8);
    __syncthreads();
#pragma unroll
    for (int i = 0; i < 4; ++i) {
      const int ao = (q << 10) + ((wm + i * 16 + mr) << 3);
      const f16x8 ah = *(const f16x8*)(lAh + ao);
      const f16x8 al = *(const f16x8*)(lAl + ao);
#pragma unroll
      for (int j = 0; j < 4; ++j) {
        const int bo = (q << 10) + ((wn + j * 16 + mr) << 3);
        const f16x8 bh = *(const f16x8*)(lBh + bo);
        const f16x8 bl = *(const f16x8*)(lBl + bo);
        acc[i][j] = __builtin_amdgcn_mfma_f32_16x16x32_f16(ah, bh, acc[i][j], 0, 0, 0);
        acc[i][j] = __builtin_amdgcn_mfma_f32_16x16x32_f16(ah, bl, acc[i][j], 0, 0, 0);
        acc[i][j] = __builtin_amdgcn_mfma_f32_16x16x32_f16(al, bh, acc[i][j], 0, 0, 0);
      }
    }
    __syncthreads();
  }

#pragma unroll
  for (int i = 0; i < 4; ++i) {
#pragma unroll
    for (int j = 0; j < 4; ++j) {
      const int col = bn0 + wn + j * 16 + mr;
      const float bv = bias[col];
#pragma unroll
      for (int r = 0; r < 4; ++r) {
        const int row = bm0 + wm + i * 16 + q * 4 + r;
        float v = softplus_f(acc[i][j][r] + bv);
        v = fminf(fmaxf(v, 1e-4f), 10.f);
        C[(size_t)row * N + col] = v;
      }
    }
  }
}

// ---------- causal depthwise conv(4) + bias + silu (fp32 + split-fp16 out) ----
__global__ __launch_bounds__(256) void conv_silu_k(const float* __restrict__ left,
                                                   const float* __restrict__ cw,
                                                   const float* __restrict__ cb,
                                                   float* __restrict__ xc,
                                                   half_t* __restrict__ xch,
                                                   half_t* __restrict__ xcl) {
  const int idx = blockIdx.x * 256 + threadIdx.x;  // over TOK*DI
  const int d = idx & (DI - 1);
  const int bt = idx >> 11;
  const int t = bt & (LL - 1);
  const float4 wv = *(const float4*)(cw + (size_t)d * 4);
  float acc = cb[d];
  const size_t base = (size_t)idx;
  if (t >= 3) {
    acc += left[base - 3 * DI] * wv.x + left[base - 2 * DI] * wv.y +
           left[base - DI] * wv.z + left[base] * wv.w;
  } else {
    acc += left[base] * wv.w;
    if (t >= 1) acc += left[base - DI] * wv.z;
    if (t >= 2) acc += left[base - 2 * DI] * wv.y;
  }
  const float v = silu_f(acc);
  xc[base] = v;
  const half_t h = (half_t)v;
  xch[base] = h;
  xcl[base] = (half_t)(v - (float)h);
}

// ---------- B/C projection: PACKED bc[row][2n]=B_n, bc[row][2n+1]=C_n ----------
__global__ __launch_bounds__(256) void bc_k(const float* __restrict__ xc,
                                            const float* __restrict__ wB,
                                            const float* __restrict__ wC,
                                            float* __restrict__ bc) {
  __shared__ float xs[DI];
  __shared__ float red[8][32];
  const int row = blockIdx.x;
  const float* xr = xc + (size_t)row * DI;
  for (int i = threadIdx.x; i < DI; i += 256) xs[i] = xr[i];
  __syncthreads();
  const int n = threadIdx.x & 31, part = threadIdx.x >> 5;
  const float* wr = (n < 16 ? wB + (size_t)n * DI : wC + (size_t)(n - 16) * DI) + part * 256;
  const float* xp = xs + part * 256;
  float s = 0.f;
#pragma unroll 4
  for (int k = 0; k < 256; ++k) s = fmaf(xp[k], wr[k], s);
  red[part][n] = s;
  __syncthreads();
  if (part == 0) {
    float t = 0.f;
#pragma unroll
    for (int j = 0; j < 8; ++j) t += red[j][n];
    const int idx = (n < 16) ? (2 * n) : (2 * (n - 16) + 1);   // interleave B,C
    bc[(size_t)row * 32 + idx] = t;
  }
}

// ---------- selective scan: DPP reduce, packed LDS, prefetch pipeline ----------
// grid 512 = 4 batches x 128 channel-blocks; 256 thr; lane = ch*16 + n per row16.
#define ST 32
__global__ __launch_bounds__(256) void scan_k(const float* __restrict__ delta,
                                              const float* __restrict__ xc,
                                              const float* __restrict__ gate,
                                              const float* __restrict__ bcp,
                                              const float* __restrict__ A_log,
                                              float* __restrict__ y) {
  __shared__ float dx2[16 * 68];   // [ch][tt] float2 {delta,x}, stride 68 words (b128-aligned, conflict-free)
  __shared__ float bcs[ST * 32];   // [tt][2n]={B,C}
  __shared__ float ys[ST * 16];    // [tt][ch]
  const int tid = threadIdx.x;
  const int b  = blockIdx.x >> 7;
  const int d0 = (blockIdx.x & 127) << 4;
  const int n  = tid & 15;
  const int ch = tid >> 4;
  const float An = -softplus_f(A_log[n]);

  // staging slots: s0=tid (tt=t_a), s1=tid+256 (tt=t_a+16)
  const int t_a = tid >> 4, c_a = tid & 15;
  const int t_b = t_a + 16;

  float h = 0.f;
  const size_t batch_base = (size_t)b * LL * DI + d0;
  const size_t batch_bc   = (size_t)b * LL * 32;

  // ---- prefetch + stage iter 0 ----
  size_t rb_cur = batch_base;
  float g0, g1;
  {
    const size_t ra = rb_cur + (size_t)t_a * DI + c_a;
    const size_t rbx = rb_cur + (size_t)t_b * DI + c_a;
    const float d0v = delta[ra], x0v = xc[ra];
    const float d1v = delta[rbx], x1v = xc[rbx];
    g0 = gate[ra]; g1 = gate[rbx];
    const float2 b0 = *(const float2*)&bcp[batch_bc + (size_t)t_a * 32 + 2 * c_a];
    const float2 b1 = *(const float2*)&bcp[batch_bc + (size_t)t_b * 32 + 2 * c_a];
    *(float2*)&dx2[c_a * 68 + t_a * 2] = make_float2(d0v, x0v);
    *(float2*)&dx2[c_a * 68 + t_b * 2] = make_float2(d1v, x1v);
    *(float2*)&bcs[t_a * 32 + 2 * c_a] = b0;
    *(float2*)&bcs[t_b * 32 + 2 * c_a] = b1;
  }
  __syncthreads();

  for (int it = 0; it < LL / ST; ++it) {
    // ---- prefetch next tile into regs (latency hidden behind compute) ----
    float nd0, nx0, ng0, nd1, nx1, ng1;
    float2 nb0, nb1;
    const size_t rb_nxt = batch_base + (size_t)(it + 1) * ST * DI;
    if (it + 1 < LL / ST) {
      const size_t ra = rb_nxt + (size_t)t_a * DI + c_a;
      const size_t rbx = rb_nxt + (size_t)t_b * DI + c_a;
      nd0 = delta[ra]; nx0 = xc[ra]; ng0 = gate[ra];
      nd1 = delta[rbx]; nx1 = xc[rbx]; ng1 = gate[rbx];
      const size_t bcb = batch_bc + (size_t)(it + 1) * ST * 32;
      nb0 = *(const float2*)&bcp[bcb + (size_t)t_a * 32 + 2 * c_a];
      nb1 = *(const float2*)&bcp[bcb + (size_t)t_b * 32 + 2 * c_a];
    }

    // ---- compute 32 steps ----
    const float* dxp = &dx2[ch * 68];
#pragma unroll
    for (int tt = 0; tt < ST; tt += 2) {
      const float4 v = *(const float4*)&dxp[tt * 2];             // d0 x0 d1 x1 (broadcast)
      const float2 bc0 = *(const float2*)&bcs[tt * 32 + 2 * n];
      const float2 bc1 = *(const float2*)&bcs[(tt + 1) * 32 + 2 * n];
      // step tt
      float ab = __expf(v.x * An);
      h = fmaf(ab, h, v.x * v.y * bc0.x);
      float p = h * bc0.y;
      p = DPP_ADD(p, 0x111); p = DPP_ADD(p, 0x112);
      p = DPP_ADD(p, 0x114); p = DPP_ADD(p, 0x118);
      if (n == 15) ys[tt * 16 + ch] = p;
      // step tt+1
      ab = __expf(v.z * An);
      h = fmaf(ab, h, v.z * v.w * bc1.x);
      p = h * bc1.y;
      p = DPP_ADD(p, 0x111); p = DPP_ADD(p, 0x112);
      p = DPP_ADD(p, 0x114); p = DPP_ADD(p, 0x118);
      if (n == 15) ys[(tt + 1) * 16 + ch] = p;
    }
    __syncthreads();   // ys complete; LDS tile consumed

    // ---- stage next tile + gated y store for current ----
    if (it + 1 < LL / ST) {
      *(float2*)&dx2[c_a * 68 + t_a * 2] = make_float2(nd0, nx0);
      *(float2*)&dx2[c_a * 68 + t_b * 2] = make_float2(nd1, nx1);
      *(float2*)&bcs[t_a * 32 + 2 * c_a] = nb0;
      *(float2*)&bcs[t_b * 32 + 2 * c_a] = nb1;
    }
    y[rb_cur + (size_t)t_a * DI + c_a] = ys[t_a * 16 + c_a] * g0;
    y[rb_cur + (size_t)t_b * DI + c_a] = ys[t_b * 16 + c_a] * g1;
    g0 = ng0; g1 = ng1;
    rb_cur = rb_nxt;
    __syncthreads();   // staging + ys reads done before next compute
  }
}

// ---------- layernorm over d_inner (fp16 out for MFMA consumer) ----------
__global__ __launch_bounds__(256) void ln_k(const float* __restrict__ y,
                                            const float* __restrict__ gam,
                                            const float* __restrict__ bet,
                                            half_t* __restrict__ outn) {
  const int row = blockIdx.x;
  const int tid = threadIdx.x;
  const float* yr = y + (size_t)row * DI;
  const float4 v0 = ((const float4*)yr)[tid];
  const float4 v1 = ((const float4*)yr)[tid + 256];
  float s = v0.x + v0.y + v0.z + v0.w + v1.x + v1.y + v1.z + v1.w;
  float q = v0.x * v0.x + v0.y * v0.y + v0.z * v0.z + v0.w * v0.w +
            v1.x * v1.x + v1.y * v1.y + v1.z * v1.z + v1.w * v1.w;
  for (int off = 32; off > 0; off >>= 1) {
    s += __shfl_down(s, off);
    q += __shfl_down(q, off);
  }
  __shared__ float sred[4], qred[4];
  const int wid = tid >> 6;
  if ((tid & 63) == 0) { sred[wid] = s; qred[wid] = q; }
  __syncthreads();
  s = sred[0] + sred[1] + sred[2] + sred[3];
  q = qred[0] + qred[1] + qred[2] + qred[3];
  const float mu = s * (1.f / DI);
  const float rs = rsqrtf(q * (1.f / DI) - mu * mu + 1e-5f);
  half_t* orow = outn + (size_t)row * DI;
  const int c0 = tid * 4, c1 = (tid + 256) * 4;
  f16x4 o;
  o[0] = (half_t)((v0.x - mu) * rs * gam[c0 + 0] + bet[c0 + 0]);
  o[1] = (half_t)((v0.y - mu) * rs * gam[c0 + 1] + bet[c0 + 1]);
  o[2] = (half_t)((v0.z - mu) * rs * gam[c0 + 2] + bet[c0 + 2]);
  o[3] = (half_t)((v0.w - mu) * rs * gam[c0 + 3] + bet[c0 + 3]);
  ((f16x4*)orow)[tid] = o;
  o[0] = (half_t)((v1.x - mu) * rs * gam[c1 + 0] + bet[c1 + 0]);
  o[1] = (half_t)((v1.y - mu) * rs * gam[c1 + 1] + bet[c1 + 1]);
  o[2] = (half_t)((v1.z - mu) * rs * gam[c1 + 2] + bet[c1 + 2]);
  o[3] = (half_t)((v1.w - mu) * rs * gam[c1 + 3] + bet[c1 + 3]);
  ((f16x4*)orow)[tid + 256] = o;
}

// ---------- host launch ----------
extern "C" void kernel_launch(void* const* d_in, const int* in_sizes, int n_in,
                              void* d_out, int out_size, void* d_ws, size_t ws_size,
                              hipStream_t stream) {
  const float* x       = (const float*)d_in[0];
  const float* W_left  = (const float*)d_in[1];
  const float* conv_w  = (const float*)d_in[2];
  const float* conv_b  = (const float*)d_in[3];
  const float* W_delta = (const float*)d_in[4];
  const float* b_delta = (const float*)d_in[5];
  const float* W_B     = (const float*)d_in[6];
  const float* W_C     = (const float*)d_in[7];
  const float* A_log   = (const float*)d_in[8];
  const float* W_right = (const float*)d_in[9];
  const float* ln_g    = (const float*)d_in[10];
  const float* ln_b    = (const float*)d_in[11];
  const float* W_out   = (const float*)d_in[12];

  float* buf = nullptr;
  hipGetSymbolAddress((void**)&buf, HIP_SYMBOL(g_buf));
  half_t* xh   = (half_t*)(buf + 0);
  half_t* wlh  = (half_t*)(buf + 4194304);
  half_t* wrh  = (half_t*)(buf + 5242880);
  half_t* wdh  = (half_t*)(buf + 6291456);
  half_t* wdl  = (half_t*)(buf + 8388608);
  half_t* woh  = (half_t*)(buf + 10485760);
  float* left  = buf + 11534336;
  float* xc    = buf + 28311552;
  half_t* xch  = (half_t*)(buf + 45088768);
  half_t* xcl  = (half_t*)(buf + 53477376);
  float* dlt   = buf + 61865984;
  float* gate  = buf + 78643200;
  float* yv    = buf + 95420416;
  half_t* nrmh = (half_t*)(buf + 112197632);
  float* bc    = buf + 120586240;

  // fp32 -> fp16 staging
  f2h_k<<<8192, 256, 0, stream>>>(x, xh, TOK * DM / 4);
  f2h_k<<<2048, 256, 0, stream>>>(W_left, wlh, DI * DM / 4);
  f2h_k<<<2048, 256, 0, stream>>>(W_right, wrh, DI * DM / 4);
  f2h_k<<<2048, 256, 0, stream>>>(W_out, woh, DM * DI / 4);
  f2h2_k<<<4096, 256, 0, stream>>>(W_delta, wdh, wdl, DI * DI / 4);

  // left = x @ W_left^T
  gemm_mfma<0><<<dim3(DI / 128, TOK / 128), 256, 0, stream>>>(xh, wlh, nullptr, left, TOK, DI, DM);
  // xc = silu(causal_conv(left))  (fp32 + hi/lo fp16)
  conv_silu_k<<<TOK * DI / 256, 256, 0, stream>>>(left, conv_w, conv_b, xc, xch, xcl);
  // gate = silu(x @ W_right^T)
  gemm_mfma<1><<<dim3(DI / 128, TOK / 128), 256, 0, stream>>>(xh, wrh, nullptr, gate, TOK, DI, DM);
  // delta = clip(softplus(xc @ W_delta^T + b_delta))  [split fp16 ~= fp32]
  gemm_mfma_split<<<dim3(DI / 128, TOK / 128), 256, 0, stream>>>(xch, xcl, wdh, wdl, b_delta, dlt, TOK, DI, DI);
  // B/C projections (packed interleaved output)
  bc_k<<<TOK, 256, 0, stream>>>(xc, W_B, W_C, bc);
  // selective scan with fused gate (DPP reduce + prefetch pipeline)
  scan_k<<<512, 256, 0, stream>>>(dlt, xc, gate, bc, A_log, yv);
  // layernorm -> fp16
  ln_k<<<TOK, 256, 0, stream>>>(yv, ln_g, ln_b, nrmh);
  // out = nrm @ W_out^T  (fp32 store to d_out)
  gemm_mfma<0><<<dim3(DM / 128, TOK / 128), 256, 0, stream>>>(nrmh, woh, nullptr, (float*)d_out, TOK, DM, DI);
}

// Round 7
// 1119.400 us; speedup vs baseline: 2.9730x; 1.3508x over previous
//
#include <hip/hip_runtime.h>
#include <cstddef>

#define LL 2048
#define TOK 8192   // B*L = 4*2048
#define DM 1024
#define DI 2048
#define NS 16

typedef _Float16 half_t;
typedef __attribute__((ext_vector_type(8))) _Float16 f16x8;
typedef __attribute__((ext_vector_type(4))) _Float16 f16x4;
typedef __attribute__((ext_vector_type(4))) float f32x4;

// ---------- helpers ----------
__device__ __forceinline__ float softplus_f(float x) {
  return fmaxf(x, 0.f) + log1pf(__expf(-fabsf(x)));
}
__device__ __forceinline__ float silu_f(float x) {
  return x / (1.f + __expf(-x));
}
__device__ __forceinline__ void gload_lds16(const void* g, void* l) {
  __builtin_amdgcn_global_load_lds((const __attribute__((address_space(1))) void*)g,
                                   (__attribute__((address_space(3))) void*)l, 16, 0, 0);
}
// DPP row_shr add: after ctrl 0x111,0x112,0x114,0x118 lane15 of each row16 holds the row sum
#define DPP_ADD(v, ctrl) \
  ((v) + __int_as_float(__builtin_amdgcn_update_dpp(0, __float_as_int(v), (ctrl), 0xf, 0xf, true)))

// ---------- static scratch (float units) ----------
//  xh    @ 0            (4,194,304)   x as fp16
//  wlh   @ 4,194,304    (1,048,576)
//  wrh   @ 5,242,880    (1,048,576)
//  wdh   @ 6,291,456    (2,097,152)   W_delta hi
//  wdl   @ 8,388,608    (2,097,152)   W_delta lo
//  woh   @ 10,485,760   (1,048,576)
//  left  @ 11,534,336   (16,777,216)
//  xc    @ 28,311,552   (16,777,216)
//  xch   @ 45,088,768   (8,388,608)   xc hi fp16
//  xcl   @ 53,477,376   (8,388,608)   xc lo fp16
//  dlt   @ 61,865,984   (16,777,216)
//  gate  @ 78,643,200   (16,777,216)
//  y     @ 95,420,416   (16,777,216)
//  nrmh  @ 112,197,632  (8,388,608)   LN out fp16
//  bc    @ 120,586,240  (262,144)     packed: [row][2n]=B_n, [2n+1]=C_n
//  wbch  @ 120,848,384  (32,768)      [W_B;W_C] as fp16 [32][2048]
__device__ float g_buf[120881152];

// ---------- fp32 -> fp16 staging ----------
__global__ __launch_bounds__(256) void f2h_k(const float* __restrict__ in,
                                             half_t* __restrict__ out, int n4) {
  const int i = blockIdx.x * 256 + threadIdx.x;
  if (i >= n4) return;
  const float4 v = ((const float4*)in)[i];
  f16x4 o;
  o[0] = (half_t)v.x; o[1] = (half_t)v.y; o[2] = (half_t)v.z; o[3] = (half_t)v.w;
  ((f16x4*)out)[i] = o;
}

// ---------- fp32 -> (hi, lo) fp16 split staging ----------
__global__ __launch_bounds__(256) void f2h2_k(const float* __restrict__ in,
                                              half_t* __restrict__ hi,
                                              half_t* __restrict__ lo, int n4) {
  const int i = blockIdx.x * 256 + threadIdx.x;
  if (i >= n4) return;
  const float4 v = ((const float4*)in)[i];
  f16x4 h, l;
  h[0] = (half_t)v.x; h[1] = (half_t)v.y; h[2] = (half_t)v.z; h[3] = (half_t)v.w;
  l[0] = (half_t)(v.x - (float)h[0]);
  l[1] = (half_t)(v.y - (float)h[1]);
  l[2] = (half_t)(v.z - (float)h[2]);
  l[3] = (half_t)(v.w - (float)h[3]);
  ((f16x4*)hi)[i] = h;
  ((f16x4*)lo)[i] = l;
}

// ---------- fp16 MFMA GEMM: C[M,N] = act(A[M,K] @ W[N,K]^T + bias), fp32 out --
template <int ACT>   // 0 none, 1 silu
__global__ __launch_bounds__(256) void gemm_mfma(const half_t* __restrict__ A,
                                                 const half_t* __restrict__ W,
                                                 const float* __restrict__ bias,
                                                 float* __restrict__ C,
                                                 int M, int N, int K) {
  __shared__ half_t lA[4096];   // 8 KB
  __shared__ half_t lB[4096];   // 8 KB
  const int tid = threadIdx.x;
  const int bm0 = blockIdx.y * 128, bn0 = blockIdx.x * 128;
  const int lane = tid & 63, wave = tid >> 6;
  const int q = lane >> 4, mr = lane & 15;
  const int wm = (wave >> 1) * 64, wn = (wave & 1) * 64;
  const int flat0 = tid, flat1 = tid + 256;
  const int kc0 = flat0 >> 7, r0 = flat0 & 127;
  const int kc1 = flat1 >> 7, r1 = flat1 & 127;

  f32x4 acc[4][4];
#pragma unroll
  for (int i = 0; i < 4; ++i)
#pragma unroll
    for (int j = 0; j < 4; ++j) acc[i][j] = (f32x4){0.f, 0.f, 0.f, 0.f};

  for (int k0 = 0; k0 < K; k0 += 32) {
    gload_lds16(A + (size_t)(bm0 + r0) * K + k0 + kc0 * 8, lA + (size_t)flat0 * 8);
    gload_lds16(A + (size_t)(bm0 + r1) * K + k0 + kc1 * 8, lA + (size_t)flat1 * 8);
    gload_lds16(W + (size_t)(bn0 + r0) * K + k0 + kc0 * 8, lB + (size_t)flat0 * 8);
    gload_lds16(W + (size_t)(bn0 + r1) * K + k0 + kc1 * 8, lB + (size_t)flat1 * 8);
    __syncthreads();
    f16x8 af[4], bg[4];
#pragma unroll
    for (int t = 0; t < 4; ++t) {
      af[t] = *(const f16x8*)(lA + ((q << 10) + ((wm + t * 16 + mr) << 3)));
      bg[t] = *(const f16x8*)(lB + ((q << 10) + ((wn + t * 16 + mr) << 3)));
    }
#pragma unroll
    for (int i = 0; i < 4; ++i)
#pragma unroll
      for (int j = 0; j < 4; ++j)
        acc[i][j] = __builtin_amdgcn_mfma_f32_16x16x32_f16(af[i], bg[j], acc[i][j], 0, 0, 0);
    __syncthreads();
  }

#pragma unroll
  for (int i = 0; i < 4; ++i) {
#pragma unroll
    for (int j = 0; j < 4; ++j) {
      const int col = bn0 + wn + j * 16 + mr;
      const float bv = bias ? bias[col] : 0.f;
#pragma unroll
      for (int r = 0; r < 4; ++r) {
        const int row = bm0 + wm + i * 16 + q * 4 + r;
        float v = acc[i][j][r] + bv;
        if (ACT == 1) v = silu_f(v);
        C[(size_t)row * N + col] = v;
      }
    }
  }
}

// ---------- split-fp16 MFMA GEMM (effective ~fp32): delta projection ----------
__global__ __launch_bounds__(256) void gemm_mfma_split(const half_t* __restrict__ Ah,
                                                       const half_t* __restrict__ Al,
                                                       const half_t* __restrict__ Wh,
                                                       const half_t* __restrict__ Wl,
                                                       const float* __restrict__ bias,
                                                       float* __restrict__ C,
                                                       int M, int N, int K) {
  __shared__ half_t lAh[4096], lAl[4096], lBh[4096], lBl[4096];  // 32 KB
  const int tid = threadIdx.x;
  const int bm0 = blockIdx.y * 128, bn0 = blockIdx.x * 128;
  const int lane = tid & 63, wave = tid >> 6;
  const int q = lane >> 4, mr = lane & 15;
  const int wm = (wave >> 1) * 64, wn = (wave & 1) * 64;
  const int flat0 = tid, flat1 = tid + 256;
  const int kc0 = flat0 >> 7, r0 = flat0 & 127;
  const int kc1 = flat1 >> 7, r1 = flat1 & 127;

  f32x4 acc[4][4];
#pragma unroll
  for (int i = 0; i < 4; ++i)
#pragma unroll
    for (int j = 0; j < 4; ++j) acc[i][j] = (f32x4){0.f, 0.f, 0.f, 0.f};

  for (int k0 = 0; k0 < K; k0 += 32) {
    const size_t ga0 = (size_t)(bm0 + r0) * K + k0 + kc0 * 8;
    const size_t ga1 = (size_t)(bm0 + r1) * K + k0 + kc1 * 8;
    const size_t gb0 = (size_t)(bn0 + r0) * K + k0 + kc0 * 8;
    const size_t gb1 = (size_t)(bn0 + r1) * K + k0 + kc1 * 8;
    gload_lds16(Ah + ga0, lAh + (size_t)flat0 * 8);
    gload_lds16(Ah + ga1, lAh + (size_t)flat1 * 8);
    gload_lds16(Al + ga0, lAl + (size_t)flat0 * 8);
    gload_lds16(Al + ga1, lAl + (size_t)flat1 * 8);
    gload_lds16(Wh + gb0, lBh + (size_t)flat0 * 8);
    gload_lds16(Wh + gb1, lBh + (size_t)flat1 * 8);
    gload_lds16(Wl + gb0, lBl + (size_t)flat0 * 8);
    gload_lds16(Wl + gb1, lBl + (size_t)flat1 * 8);
    __syncthreads();
#pragma unroll
    for (int i = 0; i < 4; ++i) {
      const int ao = (q << 10) + ((wm + i * 16 + mr) << 3);
      const f16x8 ah = *(const f16x8*)(lAh + ao);
      const f16x8 al = *(const f16x8*)(lAl + ao);
#pragma unroll
      for (int j = 0; j < 4; ++j) {
        const int bo = (q << 10) + ((wn + j * 16 + mr) << 3);
        const f16x8 bh = *(const f16x8*)(lBh + bo);
        const f16x8 bl = *(const f16x8*)(lBl + bo);
        acc[i][j] = __builtin_amdgcn_mfma_f32_16x16x32_f16(ah, bh, acc[i][j], 0, 0, 0);
        acc[i][j] = __builtin_amdgcn_mfma_f32_16x16x32_f16(ah, bl, acc[i][j], 0, 0, 0);
        acc[i][j] = __builtin_amdgcn_mfma_f32_16x16x32_f16(al, bh, acc[i][j], 0, 0, 0);
      }
    }
    __syncthreads();
  }

#pragma unroll
  for (int i = 0; i < 4; ++i) {
#pragma unroll
    for (int j = 0; j < 4; ++j) {
      const int col = bn0 + wn + j * 16 + mr;
      const float bv = bias[col];
#pragma unroll
      for (int r = 0; r < 4; ++r) {
        const int row = bm0 + wm + i * 16 + q * 4 + r;
        float v = softplus_f(acc[i][j][r] + bv);
        v = fminf(fmaxf(v, 1e-4f), 10.f);
        C[(size_t)row * N + col] = v;
      }
    }
  }
}

// ---------- skinny MFMA GEMM for B/C: bc[M,32] = xch @ [W_B;W_C]^T ----------
// 64 blocks x 128-row tiles, 4 waves each 32 rows x 32 cols (2x2 MFMA tiles).
// Epilogue writes interleaved: bc[row][2n]=B_n (j=0), bc[row][2n+1]=C_n (j=1).
__global__ __launch_bounds__(256) void bc_mfma(const half_t* __restrict__ A,
                                               const half_t* __restrict__ Wbc,
                                               float* __restrict__ bc) {
  __shared__ half_t lA[4096];   // [kc4][128][8]  8 KB
  __shared__ half_t lB[1024];   // [kc4][32][8]   2 KB
  const int tid = threadIdx.x;
  const int bm0 = blockIdx.x * 128;
  const int lane = tid & 63, wave = tid >> 6;
  const int q = lane >> 4, mr = lane & 15;
  const int wm = wave * 32;
  const int flat1 = tid + 256;
  const int kcA0 = tid >> 7, rA0 = tid & 127;
  const int kcA1 = flat1 >> 7, rA1 = flat1 & 127;
  const int kcB = tid >> 5, rB = tid & 31;   // threads 0..127

  f32x4 acc[2][2];
#pragma unroll
  for (int i = 0; i < 2; ++i)
#pragma unroll
    for (int j = 0; j < 2; ++j) acc[i][j] = (f32x4){0.f, 0.f, 0.f, 0.f};

  for (int k0 = 0; k0 < DI; k0 += 32) {
    gload_lds16(A + (size_t)(bm0 + rA0) * DI + k0 + kcA0 * 8, lA + (size_t)tid * 8);
    gload_lds16(A + (size_t)(bm0 + rA1) * DI + k0 + kcA1 * 8, lA + (size_t)flat1 * 8);
    if (tid < 128)
      gload_lds16(Wbc + (size_t)rB * DI + k0 + kcB * 8, lB + (size_t)tid * 8);
    __syncthreads();
    f16x8 af[2], bg[2];
#pragma unroll
    for (int t = 0; t < 2; ++t) {
      af[t] = *(const f16x8*)(lA + ((q << 10) + ((wm + t * 16 + mr) << 3)));
      bg[t] = *(const f16x8*)(lB + ((q << 8) + ((t * 16 + mr) << 3)));
    }
#pragma unroll
    for (int i = 0; i < 2; ++i)
#pragma unroll
      for (int j = 0; j < 2; ++j)
        acc[i][j] = __builtin_amdgcn_mfma_f32_16x16x32_f16(af[i], bg[j], acc[i][j], 0, 0, 0);
    __syncthreads();
  }

#pragma unroll
  for (int i = 0; i < 2; ++i) {
#pragma unroll
    for (int j = 0; j < 2; ++j) {
#pragma unroll
      for (int r = 0; r < 4; ++r) {
        const int row = bm0 + wm + i * 16 + q * 4 + r;
        bc[(size_t)row * 32 + 2 * mr + j] = acc[i][j][r];
      }
    }
  }
}

// ---------- causal depthwise conv(4) + bias + silu (fp32 + split-fp16 out) ----
__global__ __launch_bounds__(256) void conv_silu_k(const float* __restrict__ left,
                                                   const float* __restrict__ cw,
                                                   const float* __restrict__ cb,
                                                   float* __restrict__ xc,
                                                   half_t* __restrict__ xch,
                                                   half_t* __restrict__ xcl) {
  const int idx = blockIdx.x * 256 + threadIdx.x;  // over TOK*DI
  const int d = idx & (DI - 1);
  const int bt = idx >> 11;
  const int t = bt & (LL - 1);
  const float4 wv = *(const float4*)(cw + (size_t)d * 4);
  float acc = cb[d];
  const size_t base = (size_t)idx;
  if (t >= 3) {
    acc += left[base - 3 * DI] * wv.x + left[base - 2 * DI] * wv.y +
           left[base - DI] * wv.z + left[base] * wv.w;
  } else {
    acc += left[base] * wv.w;
    if (t >= 1) acc += left[base - DI] * wv.z;
    if (t >= 2) acc += left[base - 2 * DI] * wv.y;
  }
  const float v = silu_f(acc);
  xc[base] = v;
  const half_t h = (half_t)v;
  xch[base] = h;
  xcl[base] = (half_t)(v - (float)h);
}

// ---------- selective scan: DPP reduce, packed LDS, prefetch pipeline ----------
#define ST 32
__global__ __launch_bounds__(256) void scan_k(const float* __restrict__ delta,
                                              const float* __restrict__ xc,
                                              const float* __restrict__ gate,
                                              const float* __restrict__ bcp,
                                              const float* __restrict__ A_log,
                                              float* __restrict__ y) {
  __shared__ float dx2[16 * 68];
  __shared__ float bcs[ST * 32];
  __shared__ float ys[ST * 16];
  const int tid = threadIdx.x;
  const int b  = blockIdx.x >> 7;
  const int d0 = (blockIdx.x & 127) << 4;
  const int n  = tid & 15;
  const int ch = tid >> 4;
  const float An = -softplus_f(A_log[n]);

  const int t_a = tid >> 4, c_a = tid & 15;
  const int t_b = t_a + 16;

  float h = 0.f;
  const size_t batch_base = (size_t)b * LL * DI + d0;
  const size_t batch_bc   = (size_t)b * LL * 32;

  size_t rb_cur = batch_base;
  float g0, g1;
  {
    const size_t ra = rb_cur + (size_t)t_a * DI + c_a;
    const size_t rbx = rb_cur + (size_t)t_b * DI + c_a;
    const float d0v = delta[ra], x0v = xc[ra];
    const float d1v = delta[rbx], x1v = xc[rbx];
    g0 = gate[ra]; g1 = gate[rbx];
    const float2 b0 = *(const float2*)&bcp[batch_bc + (size_t)t_a * 32 + 2 * c_a];
    const float2 b1 = *(const float2*)&bcp[batch_bc + (size_t)t_b * 32 + 2 * c_a];
    *(float2*)&dx2[c_a * 68 + t_a * 2] = make_float2(d0v, x0v);
    *(float2*)&dx2[c_a * 68 + t_b * 2] = make_float2(d1v, x1v);
    *(float2*)&bcs[t_a * 32 + 2 * c_a] = b0;
    *(float2*)&bcs[t_b * 32 + 2 * c_a] = b1;
  }
  __syncthreads();

  for (int it = 0; it < LL / ST; ++it) {
    float nd0, nx0, ng0, nd1, nx1, ng1;
    float2 nb0, nb1;
    const size_t rb_nxt = batch_base + (size_t)(it + 1) * ST * DI;
    if (it + 1 < LL / ST) {
      const size_t ra = rb_nxt + (size_t)t_a * DI + c_a;
      const size_t rbx = rb_nxt + (size_t)t_b * DI + c_a;
      nd0 = delta[ra]; nx0 = xc[ra]; ng0 = gate[ra];
      nd1 = delta[rbx]; nx1 = xc[rbx]; ng1 = gate[rbx];
      const size_t bcb = batch_bc + (size_t)(it + 1) * ST * 32;
      nb0 = *(const float2*)&bcp[bcb + (size_t)t_a * 32 + 2 * c_a];
      nb1 = *(const float2*)&bcp[bcb + (size_t)t_b * 32 + 2 * c_a];
    }

    const float* dxp = &dx2[ch * 68];
#pragma unroll
    for (int tt = 0; tt < ST; tt += 2) {
      const float4 v = *(const float4*)&dxp[tt * 2];
      const float2 bc0 = *(const float2*)&bcs[tt * 32 + 2 * n];
      const float2 bc1 = *(const float2*)&bcs[(tt + 1) * 32 + 2 * n];
      float ab = __expf(v.x * An);
      h = fmaf(ab, h, v.x * v.y * bc0.x);
      float p = h * bc0.y;
      p = DPP_ADD(p, 0x111); p = DPP_ADD(p, 0x112);
      p = DPP_ADD(p, 0x114); p = DPP_ADD(p, 0x118);
      if (n == 15) ys[tt * 16 + ch] = p;
      ab = __expf(v.z * An);
      h = fmaf(ab, h, v.z * v.w * bc1.x);
      p = h * bc1.y;
      p = DPP_ADD(p, 0x111); p = DPP_ADD(p, 0x112);
      p = DPP_ADD(p, 0x114); p = DPP_ADD(p, 0x118);
      if (n == 15) ys[(tt + 1) * 16 + ch] = p;
    }
    __syncthreads();

    if (it + 1 < LL / ST) {
      *(float2*)&dx2[c_a * 68 + t_a * 2] = make_float2(nd0, nx0);
      *(float2*)&dx2[c_a * 68 + t_b * 2] = make_float2(nd1, nx1);
      *(float2*)&bcs[t_a * 32 + 2 * c_a] = nb0;
      *(float2*)&bcs[t_b * 32 + 2 * c_a] = nb1;
    }
    y[rb_cur + (size_t)t_a * DI + c_a] = ys[t_a * 16 + c_a] * g0;
    y[rb_cur + (size_t)t_b * DI + c_a] = ys[t_b * 16 + c_a] * g1;
    g0 = ng0; g1 = ng1;
    rb_cur = rb_nxt;
    __syncthreads();
  }
}

// ---------- layernorm over d_inner (fp16 out for MFMA consumer) ----------
__global__ __launch_bounds__(256) void ln_k(const float* __restrict__ y,
                                            const float* __restrict__ gam,
                                            const float* __restrict__ bet,
                                            half_t* __restrict__ outn) {
  const int row = blockIdx.x;
  const int tid = threadIdx.x;
  const float* yr = y + (size_t)row * DI;
  const float4 v0 = ((const float4*)yr)[tid];
  const float4 v1 = ((const float4*)yr)[tid + 256];
  float s = v0.x + v0.y + v0.z + v0.w + v1.x + v1.y + v1.z + v1.w;
  float q = v0.x * v0.x + v0.y * v0.y + v0.z * v0.z + v0.w * v0.w +
            v1.x * v1.x + v1.y * v1.y + v1.z * v1.z + v1.w * v1.w;
  for (int off = 32; off > 0; off >>= 1) {
    s += __shfl_down(s, off);
    q += __shfl_down(q, off);
  }
  __shared__ float sred[4], qred[4];
  const int wid = tid >> 6;
  if ((tid & 63) == 0) { sred[wid] = s; qred[wid] = q; }
  __syncthreads();
  s = sred[0] + sred[1] + sred[2] + sred[3];
  q = qred[0] + qred[1] + qred[2] + qred[3];
  const float mu = s * (1.f / DI);
  const float rs = rsqrtf(q * (1.f / DI) - mu * mu + 1e-5f);
  half_t* orow = outn + (size_t)row * DI;
  const int c0 = tid * 4, c1 = (tid + 256) * 4;
  f16x4 o;
  o[0] = (half_t)((v0.x - mu) * rs * gam[c0 + 0] + bet[c0 + 0]);
  o[1] = (half_t)((v0.y - mu) * rs * gam[c0 + 1] + bet[c0 + 1]);
  o[2] = (half_t)((v0.z - mu) * rs * gam[c0 + 2] + bet[c0 + 2]);
  o[3] = (half_t)((v0.w - mu) * rs * gam[c0 + 3] + bet[c0 + 3]);
  ((f16x4*)orow)[tid] = o;
  o[0] = (half_t)((v1.x - mu) * rs * gam[c1 + 0] + bet[c1 + 0]);
  o[1] = (half_t)((v1.y - mu) * rs * gam[c1 + 1] + bet[c1 + 1]);
  o[2] = (half_t)((v1.z - mu) * rs * gam[c1 + 2] + bet[c1 + 2]);
  o[3] = (half_t)((v1.w - mu) * rs * gam[c1 + 3] + bet[c1 + 3]);
  ((f16x4*)orow)[tid + 256] = o;
}

// ---------- host launch ----------
extern "C" void kernel_launch(void* const* d_in, const int* in_sizes, int n_in,
                              void* d_out, int out_size, void* d_ws, size_t ws_size,
                              hipStream_t stream) {
  const float* x       = (const float*)d_in[0];
  const float* W_left  = (const float*)d_in[1];
  const float* conv_w  = (const float*)d_in[2];
  const float* conv_b  = (const float*)d_in[3];
  const float* W_delta = (const float*)d_in[4];
  const float* b_delta = (const float*)d_in[5];
  const float* W_B     = (const float*)d_in[6];
  const float* W_C     = (const float*)d_in[7];
  const float* A_log   = (const float*)d_in[8];
  const float* W_right = (const float*)d_in[9];
  const float* ln_g    = (const float*)d_in[10];
  const float* ln_b    = (const float*)d_in[11];
  const float* W_out   = (const float*)d_in[12];

  float* buf = nullptr;
  hipGetSymbolAddress((void**)&buf, HIP_SYMBOL(g_buf));
  half_t* xh   = (half_t*)(buf + 0);
  half_t* wlh  = (half_t*)(buf + 4194304);
  half_t* wrh  = (half_t*)(buf + 5242880);
  half_t* wdh  = (half_t*)(buf + 6291456);
  half_t* wdl  = (half_t*)(buf + 8388608);
  half_t* woh  = (half_t*)(buf + 10485760);
  float* left  = buf + 11534336;
  float* xc    = buf + 28311552;
  half_t* xch  = (half_t*)(buf + 45088768);
  half_t* xcl  = (half_t*)(buf + 53477376);
  float* dlt   = buf + 61865984;
  float* gate  = buf + 78643200;
  float* yv    = buf + 95420416;
  half_t* nrmh = (half_t*)(buf + 112197632);
  float* bc    = buf + 120586240;
  half_t* wbch = (half_t*)(buf + 120848384);

  // fp32 -> fp16 staging
  f2h_k<<<8192, 256, 0, stream>>>(x, xh, TOK * DM / 4);
  f2h_k<<<2048, 256, 0, stream>>>(W_left, wlh, DI * DM / 4);
  f2h_k<<<2048, 256, 0, stream>>>(W_right, wrh, DI * DM / 4);
  f2h_k<<<2048, 256, 0, stream>>>(W_out, woh, DM * DI / 4);
  f2h2_k<<<4096, 256, 0, stream>>>(W_delta, wdh, wdl, DI * DI / 4);
  f2h_k<<<32, 256, 0, stream>>>(W_B, wbch, NS * DI / 4);
  f2h_k<<<32, 256, 0, stream>>>(W_C, wbch + NS * DI, NS * DI / 4);

  // left = x @ W_left^T
  gemm_mfma<0><<<dim3(DI / 128, TOK / 128), 256, 0, stream>>>(xh, wlh, nullptr, left, TOK, DI, DM);
  // xc = silu(causal_conv(left))  (fp32 + hi/lo fp16)
  conv_silu_k<<<TOK * DI / 256, 256, 0, stream>>>(left, conv_w, conv_b, xc, xch, xcl);
  // gate = silu(x @ W_right^T)
  gemm_mfma<1><<<dim3(DI / 128, TOK / 128), 256, 0, stream>>>(xh, wrh, nullptr, gate, TOK, DI, DM);
  // delta = clip(softplus(xc @ W_delta^T + b_delta))  [split fp16 ~= fp32]
  gemm_mfma_split<<<dim3(DI / 128, TOK / 128), 256, 0, stream>>>(xch, xcl, wdh, wdl, b_delta, dlt, TOK, DI, DI);
  // B/C projections via MFMA (interleaved output)
  bc_mfma<<<TOK / 128, 256, 0, stream>>>(xch, wbch, bc);
  // selective scan with fused gate (DPP reduce + prefetch pipeline)
  scan_k<<<512, 256, 0, stream>>>(dlt, xc, gate, bc, A_log, yv);
  // layernorm -> fp16
  ln_k<<<TOK, 256, 0, stream>>>(yv, ln_g, ln_b, nrmh);
  // out = nrm @ W_out^T  (fp32 store to d_out)
  gemm_mfma<0><<<dim3(DM / 128, TOK / 128), 256, 0, stream>>>(nrmh, woh, nullptr, (float*)d_out, TOK, DM, DI);
}

// Round 8
// 990.481 us; speedup vs baseline: 3.3599x; 1.1302x over previous
//
#include <hip/hip_runtime.h>
#include <cstddef>

#define LL 2048
#define TOK 8192   // B*L = 4*2048
#define DM 1024
#define DI 2048
#define NS 16

typedef _Float16 half_t;
typedef __attribute__((ext_vector_type(8))) _Float16 f16x8;
typedef __attribute__((ext_vector_type(4))) _Float16 f16x4;
typedef __attribute__((ext_vector_type(4))) float f32x4;

// ---------- helpers ----------
__device__ __forceinline__ float softplus_f(float x) {
  return fmaxf(x, 0.f) + log1pf(__expf(-fabsf(x)));
}
__device__ __forceinline__ float silu_f(float x) {
  return x / (1.f + __expf(-x));
}
__device__ __forceinline__ void gload_lds16(const void* g, void* l) {
  __builtin_amdgcn_global_load_lds((const __attribute__((address_space(1))) void*)g,
                                   (__attribute__((address_space(3))) void*)l, 16, 0, 0);
}
// DPP row_shr add: after ctrl 0x111,0x112,0x114,0x118 lane15 of each row16 holds the row sum
#define DPP_ADD(v, ctrl) \
  ((v) + __int_as_float(__builtin_amdgcn_update_dpp(0, __float_as_int(v), (ctrl), 0xf, 0xf, true)))

// ---------- static scratch (float units) ----------
//  xh    @ 0            (4,194,304)   x as fp16
//  wlh   @ 4,194,304    (1,048,576)
//  wrh   @ 5,242,880    (1,048,576)
//  wdh   @ 6,291,456    (2,097,152)   W_delta hi
//  wdl   @ 8,388,608    (2,097,152)   W_delta lo
//  woh   @ 10,485,760   (1,048,576)
//  left  @ 11,534,336   (16,777,216)
//  xc    @ 28,311,552   (16,777,216)
//  xch   @ 45,088,768   (8,388,608)   xc hi fp16
//  (gap  @ 53,477,376   (8,388,608)   former xcl, unused)
//  dlt   @ 61,865,984   (16,777,216)
//  gate  @ 78,643,200   (16,777,216)
//  y     @ 95,420,416   (16,777,216)
//  nrmh  @ 112,197,632  (8,388,608)   LN out fp16
//  bc    @ 120,586,240  (262,144)     packed: [row][2n]=B_n, [2n+1]=C_n
//  wbch  @ 120,848,384  (32,768)      [W_B;W_C] as fp16 [32][2048]
__device__ float g_buf[120881152];

// ---------- fp32 -> fp16 staging ----------
__global__ __launch_bounds__(256) void f2h_k(const float* __restrict__ in,
                                             half_t* __restrict__ out, int n4) {
  const int i = blockIdx.x * 256 + threadIdx.x;
  if (i >= n4) return;
  const float4 v = ((const float4*)in)[i];
  f16x4 o;
  o[0] = (half_t)v.x; o[1] = (half_t)v.y; o[2] = (half_t)v.z; o[3] = (half_t)v.w;
  ((f16x4*)out)[i] = o;
}

// ---------- fp32 -> (hi, lo) fp16 split staging ----------
__global__ __launch_bounds__(256) void f2h2_k(const float* __restrict__ in,
                                              half_t* __restrict__ hi,
                                              half_t* __restrict__ lo, int n4) {
  const int i = blockIdx.x * 256 + threadIdx.x;
  if (i >= n4) return;
  const float4 v = ((const float4*)in)[i];
  f16x4 h, l;
  h[0] = (half_t)v.x; h[1] = (half_t)v.y; h[2] = (half_t)v.z; h[3] = (half_t)v.w;
  l[0] = (half_t)(v.x - (float)h[0]);
  l[1] = (half_t)(v.y - (float)h[1]);
  l[2] = (half_t)(v.z - (float)h[2]);
  l[3] = (half_t)(v.w - (float)h[3]);
  ((f16x4*)hi)[i] = h;
  ((f16x4*)lo)[i] = l;
}

// ---------- fp16 MFMA GEMM: C[M,N] = act(A[M,K] @ W[N,K]^T + bias), fp32 out --
template <int ACT>   // 0 none, 1 silu
__global__ __launch_bounds__(256) void gemm_mfma(const half_t* __restrict__ A,
                                                 const half_t* __restrict__ W,
                                                 const float* __restrict__ bias,
                                                 float* __restrict__ C,
                                                 int M, int N, int K) {
  __shared__ half_t lA[4096];   // 8 KB
  __shared__ half_t lB[4096];   // 8 KB
  const int tid = threadIdx.x;
  const int bm0 = blockIdx.y * 128, bn0 = blockIdx.x * 128;
  const int lane = tid & 63, wave = tid >> 6;
  const int q = lane >> 4, mr = lane & 15;
  const int wm = (wave >> 1) * 64, wn = (wave & 1) * 64;
  const int flat0 = tid, flat1 = tid + 256;
  const int kc0 = flat0 >> 7, r0 = flat0 & 127;
  const int kc1 = flat1 >> 7, r1 = flat1 & 127;

  f32x4 acc[4][4];
#pragma unroll
  for (int i = 0; i < 4; ++i)
#pragma unroll
    for (int j = 0; j < 4; ++j) acc[i][j] = (f32x4){0.f, 0.f, 0.f, 0.f};

  for (int k0 = 0; k0 < K; k0 += 32) {
    gload_lds16(A + (size_t)(bm0 + r0) * K + k0 + kc0 * 8, lA + (size_t)flat0 * 8);
    gload_lds16(A + (size_t)(bm0 + r1) * K + k0 + kc1 * 8, lA + (size_t)flat1 * 8);
    gload_lds16(W + (size_t)(bn0 + r0) * K + k0 + kc0 * 8, lB + (size_t)flat0 * 8);
    gload_lds16(W + (size_t)(bn0 + r1) * K + k0 + kc1 * 8, lB + (size_t)flat1 * 8);
    __syncthreads();
    f16x8 af[4], bg[4];
#pragma unroll
    for (int t = 0; t < 4; ++t) {
      af[t] = *(const f16x8*)(lA + ((q << 10) + ((wm + t * 16 + mr) << 3)));
      bg[t] = *(const f16x8*)(lB + ((q << 10) + ((wn + t * 16 + mr) << 3)));
    }
#pragma unroll
    for (int i = 0; i < 4; ++i)
#pragma unroll
      for (int j = 0; j < 4; ++j)
        acc[i][j] = __builtin_amdgcn_mfma_f32_16x16x32_f16(af[i], bg[j], acc[i][j], 0, 0, 0);
    __syncthreads();
  }

#pragma unroll
  for (int i = 0; i < 4; ++i) {
#pragma unroll
    for (int j = 0; j < 4; ++j) {
      const int col = bn0 + wn + j * 16 + mr;
      const float bv = bias ? bias[col] : 0.f;
#pragma unroll
      for (int r = 0; r < 4; ++r) {
        const int row = bm0 + wm + i * 16 + q * 4 + r;
        float v = acc[i][j][r] + bv;
        if (ACT == 1) v = silu_f(v);
        C[(size_t)row * N + col] = v;
      }
    }
  }
}

// ---------- 2-term split GEMM: acc += Ah*Wh + Ah*Wl (W-rounding corrected) ----
// All fragments hoisted: 12 ds_read_b128 vs 32 MFMA per K-chunk.
__global__ __launch_bounds__(256) void gemm_mfma_split(const half_t* __restrict__ Ah,
                                                       const half_t* __restrict__ Wh,
                                                       const half_t* __restrict__ Wl,
                                                       const float* __restrict__ bias,
                                                       float* __restrict__ C,
                                                       int M, int N, int K) {
  __shared__ half_t lAh[4096], lBh[4096], lBl[4096];  // 24 KB
  const int tid = threadIdx.x;
  const int bm0 = blockIdx.y * 128, bn0 = blockIdx.x * 128;
  const int lane = tid & 63, wave = tid >> 6;
  const int q = lane >> 4, mr = lane & 15;
  const int wm = (wave >> 1) * 64, wn = (wave & 1) * 64;
  const int flat0 = tid, flat1 = tid + 256;
  const int kc0 = flat0 >> 7, r0 = flat0 & 127;
  const int kc1 = flat1 >> 7, r1 = flat1 & 127;

  f32x4 acc[4][4];
#pragma unroll
  for (int i = 0; i < 4; ++i)
#pragma unroll
    for (int j = 0; j < 4; ++j) acc[i][j] = (f32x4){0.f, 0.f, 0.f, 0.f};

  for (int k0 = 0; k0 < K; k0 += 32) {
    const size_t ga0 = (size_t)(bm0 + r0) * K + k0 + kc0 * 8;
    const size_t ga1 = (size_t)(bm0 + r1) * K + k0 + kc1 * 8;
    const size_t gb0 = (size_t)(bn0 + r0) * K + k0 + kc0 * 8;
    const size_t gb1 = (size_t)(bn0 + r1) * K + k0 + kc1 * 8;
    gload_lds16(Ah + ga0, lAh + (size_t)flat0 * 8);
    gload_lds16(Ah + ga1, lAh + (size_t)flat1 * 8);
    gload_lds16(Wh + gb0, lBh + (size_t)flat0 * 8);
    gload_lds16(Wh + gb1, lBh + (size_t)flat1 * 8);
    gload_lds16(Wl + gb0, lBl + (size_t)flat0 * 8);
    gload_lds16(Wl + gb1, lBl + (size_t)flat1 * 8);
    __syncthreads();
    f16x8 ah[4], bh[4], bl[4];
#pragma unroll
    for (int t = 0; t < 4; ++t) {
      const int ao = (q << 10) + ((wm + t * 16 + mr) << 3);
      const int bo = (q << 10) + ((wn + t * 16 + mr) << 3);
      ah[t] = *(const f16x8*)(lAh + ao);
      bh[t] = *(const f16x8*)(lBh + bo);
      bl[t] = *(const f16x8*)(lBl + bo);
    }
#pragma unroll
    for (int i = 0; i < 4; ++i)
#pragma unroll
      for (int j = 0; j < 4; ++j) {
        acc[i][j] = __builtin_amdgcn_mfma_f32_16x16x32_f16(ah[i], bh[j], acc[i][j], 0, 0, 0);
        acc[i][j] = __builtin_amdgcn_mfma_f32_16x16x32_f16(ah[i], bl[j], acc[i][j], 0, 0, 0);
      }
    __syncthreads();
  }

#pragma unroll
  for (int i = 0; i < 4; ++i) {
#pragma unroll
    for (int j = 0; j < 4; ++j) {
      const int col = bn0 + wn + j * 16 + mr;
      const float bv = bias[col];
#pragma unroll
      for (int r = 0; r < 4; ++r) {
        const int row = bm0 + wm + i * 16 + q * 4 + r;
        float v = softplus_f(acc[i][j][r] + bv);
        v = fminf(fmaxf(v, 1e-4f), 10.f);
        C[(size_t)row * N + col] = v;
      }
    }
  }
}

// ---------- skinny MFMA GEMM for B/C: bc[M,32] = xch @ [W_B;W_C]^T ----------
__global__ __launch_bounds__(256) void bc_mfma(const half_t* __restrict__ A,
                                               const half_t* __restrict__ Wbc,
                                               float* __restrict__ bc) {
  __shared__ half_t lA[4096];   // [kc4][128][8]  8 KB
  __shared__ half_t lB[1024];   // [kc4][32][8]   2 KB
  const int tid = threadIdx.x;
  const int bm0 = blockIdx.x * 128;
  const int lane = tid & 63, wave = tid >> 6;
  const int q = lane >> 4, mr = lane & 15;
  const int wm = wave * 32;
  const int flat1 = tid + 256;
  const int kcA0 = tid >> 7, rA0 = tid & 127;
  const int kcA1 = flat1 >> 7, rA1 = flat1 & 127;
  const int kcB = tid >> 5, rB = tid & 31;   // threads 0..127

  f32x4 acc[2][2];
#pragma unroll
  for (int i = 0; i < 2; ++i)
#pragma unroll
    for (int j = 0; j < 2; ++j) acc[i][j] = (f32x4){0.f, 0.f, 0.f, 0.f};

  for (int k0 = 0; k0 < DI; k0 += 32) {
    gload_lds16(A + (size_t)(bm0 + rA0) * DI + k0 + kcA0 * 8, lA + (size_t)tid * 8);
    gload_lds16(A + (size_t)(bm0 + rA1) * DI + k0 + kcA1 * 8, lA + (size_t)flat1 * 8);
    if (tid < 128)
      gload_lds16(Wbc + (size_t)rB * DI + k0 + kcB * 8, lB + (size_t)tid * 8);
    __syncthreads();
    f16x8 af[2], bg[2];
#pragma unroll
    for (int t = 0; t < 2; ++t) {
      af[t] = *(const f16x8*)(lA + ((q << 10) + ((wm + t * 16 + mr) << 3)));
      bg[t] = *(const f16x8*)(lB + ((q << 8) + ((t * 16 + mr) << 3)));
    }
#pragma unroll
    for (int i = 0; i < 2; ++i)
#pragma unroll
      for (int j = 0; j < 2; ++j)
        acc[i][j] = __builtin_amdgcn_mfma_f32_16x16x32_f16(af[i], bg[j], acc[i][j], 0, 0, 0);
    __syncthreads();
  }

#pragma unroll
  for (int i = 0; i < 2; ++i) {
#pragma unroll
    for (int j = 0; j < 2; ++j) {
#pragma unroll
      for (int r = 0; r < 4; ++r) {
        const int row = bm0 + wm + i * 16 + q * 4 + r;
        bc[(size_t)row * 32 + 2 * mr + j] = acc[i][j][r];
      }
    }
  }
}

// ---------- causal depthwise conv(4) + bias + silu (fp32 + fp16 out) ----------
__global__ __launch_bounds__(256) void conv_silu_k(const float* __restrict__ left,
                                                   const float* __restrict__ cw,
                                                   const float* __restrict__ cb,
                                                   float* __restrict__ xc,
                                                   half_t* __restrict__ xch) {
  const int idx = blockIdx.x * 256 + threadIdx.x;  // over TOK*DI
  const int d = idx & (DI - 1);
  const int bt = idx >> 11;
  const int t = bt & (LL - 1);
  const float4 wv = *(const float4*)(cw + (size_t)d * 4);
  float acc = cb[d];
  const size_t base = (size_t)idx;
  if (t >= 3) {
    acc += left[base - 3 * DI] * wv.x + left[base - 2 * DI] * wv.y +
           left[base - DI] * wv.z + left[base] * wv.w;
  } else {
    acc += left[base] * wv.w;
    if (t >= 1) acc += left[base - DI] * wv.z;
    if (t >= 2) acc += left[base - 2 * DI] * wv.y;
  }
  const float v = silu_f(acc);
  xc[base] = v;
  xch[base] = (half_t)v;
}

// ---------- selective scan: DPP reduce, packed LDS, prefetch pipeline ----------
#define ST 32
__global__ __launch_bounds__(256) void scan_k(const float* __restrict__ delta,
                                              const float* __restrict__ xc,
                                              const float* __restrict__ gate,
                                              const float* __restrict__ bcp,
                                              const float* __restrict__ A_log,
                                              float* __restrict__ y) {
  __shared__ float dx2[16 * 68];
  __shared__ float bcs[ST * 32];
  __shared__ float ys[ST * 16];
  const int tid = threadIdx.x;
  const int b  = blockIdx.x >> 7;
  const int d0 = (blockIdx.x & 127) << 4;
  const int n  = tid & 15;
  const int ch = tid >> 4;
  const float An = -softplus_f(A_log[n]);

  const int t_a = tid >> 4, c_a = tid & 15;
  const int t_b = t_a + 16;

  float h = 0.f;
  const size_t batch_base = (size_t)b * LL * DI + d0;
  const size_t batch_bc   = (size_t)b * LL * 32;

  size_t rb_cur = batch_base;
  float g0, g1;
  {
    const size_t ra = rb_cur + (size_t)t_a * DI + c_a;
    const size_t rbx = rb_cur + (size_t)t_b * DI + c_a;
    const float d0v = delta[ra], x0v = xc[ra];
    const float d1v = delta[rbx], x1v = xc[rbx];
    g0 = gate[ra]; g1 = gate[rbx];
    const float2 b0 = *(const float2*)&bcp[batch_bc + (size_t)t_a * 32 + 2 * c_a];
    const float2 b1 = *(const float2*)&bcp[batch_bc + (size_t)t_b * 32 + 2 * c_a];
    *(float2*)&dx2[c_a * 68 + t_a * 2] = make_float2(d0v, x0v);
    *(float2*)&dx2[c_a * 68 + t_b * 2] = make_float2(d1v, x1v);
    *(float2*)&bcs[t_a * 32 + 2 * c_a] = b0;
    *(float2*)&bcs[t_b * 32 + 2 * c_a] = b1;
  }
  __syncthreads();

  for (int it = 0; it < LL / ST; ++it) {
    float nd0, nx0, ng0, nd1, nx1, ng1;
    float2 nb0, nb1;
    const size_t rb_nxt = batch_base + (size_t)(it + 1) * ST * DI;
    if (it + 1 < LL / ST) {
      const size_t ra = rb_nxt + (size_t)t_a * DI + c_a;
      const size_t rbx = rb_nxt + (size_t)t_b * DI + c_a;
      nd0 = delta[ra]; nx0 = xc[ra]; ng0 = gate[ra];
      nd1 = delta[rbx]; nx1 = xc[rbx]; ng1 = gate[rbx];
      const size_t bcb = batch_bc + (size_t)(it + 1) * ST * 32;
      nb0 = *(const float2*)&bcp[bcb + (size_t)t_a * 32 + 2 * c_a];
      nb1 = *(const float2*)&bcp[bcb + (size_t)t_b * 32 + 2 * c_a];
    }

    const float* dxp = &dx2[ch * 68];
#pragma unroll
    for (int tt = 0; tt < ST; tt += 2) {
      const float4 v = *(const float4*)&dxp[tt * 2];
      const float2 bc0 = *(const float2*)&bcs[tt * 32 + 2 * n];
      const float2 bc1 = *(const float2*)&bcs[(tt + 1) * 32 + 2 * n];
      float ab = __expf(v.x * An);
      h = fmaf(ab, h, v.x * v.y * bc0.x);
      float p = h * bc0.y;
      p = DPP_ADD(p, 0x111); p = DPP_ADD(p, 0x112);
      p = DPP_ADD(p, 0x114); p = DPP_ADD(p, 0x118);
      if (n == 15) ys[tt * 16 + ch] = p;
      ab = __expf(v.z * An);
      h = fmaf(ab, h, v.z * v.w * bc1.x);
      p = h * bc1.y;
      p = DPP_ADD(p, 0x111); p = DPP_ADD(p, 0x112);
      p = DPP_ADD(p, 0x114); p = DPP_ADD(p, 0x118);
      if (n == 15) ys[(tt + 1) * 16 + ch] = p;
    }
    __syncthreads();

    if (it + 1 < LL / ST) {
      *(float2*)&dx2[c_a * 68 + t_a * 2] = make_float2(nd0, nx0);
      *(float2*)&dx2[c_a * 68 + t_b * 2] = make_float2(nd1, nx1);
      *(float2*)&bcs[t_a * 32 + 2 * c_a] = nb0;
      *(float2*)&bcs[t_b * 32 + 2 * c_a] = nb1;
    }
    y[rb_cur + (size_t)t_a * DI + c_a] = ys[t_a * 16 + c_a] * g0;
    y[rb_cur + (size_t)t_b * DI + c_a] = ys[t_b * 16 + c_a] * g1;
    g0 = ng0; g1 = ng1;
    rb_cur = rb_nxt;
    __syncthreads();
  }
}

// ---------- layernorm over d_inner (fp16 out for MFMA consumer) ----------
__global__ __launch_bounds__(256) void ln_k(const float* __restrict__ y,
                                            const float* __restrict__ gam,
                                            const float* __restrict__ bet,
                                            half_t* __restrict__ outn) {
  const int row = blockIdx.x;
  const int tid = threadIdx.x;
  const float* yr = y + (size_t)row * DI;
  const float4 v0 = ((const float4*)yr)[tid];
  const float4 v1 = ((const float4*)yr)[tid + 256];
  float s = v0.x + v0.y + v0.z + v0.w + v1.x + v1.y + v1.z + v1.w;
  float q = v0.x * v0.x + v0.y * v0.y + v0.z * v0.z + v0.w * v0.w +
            v1.x * v1.x + v1.y * v1.y + v1.z * v1.z + v1.w * v1.w;
  for (int off = 32; off > 0; off >>= 1) {
    s += __shfl_down(s, off);
    q += __shfl_down(q, off);
  }
  __shared__ float sred[4], qred[4];
  const int wid = tid >> 6;
  if ((tid & 63) == 0) { sred[wid] = s; qred[wid] = q; }
  __syncthreads();
  s = sred[0] + sred[1] + sred[2] + sred[3];
  q = qred[0] + qred[1] + qred[2] + qred[3];
  const float mu = s * (1.f / DI);
  const float rs = rsqrtf(q * (1.f / DI) - mu * mu + 1e-5f);
  half_t* orow = outn + (size_t)row * DI;
  const int c0 = tid * 4, c1 = (tid + 256) * 4;
  f16x4 o;
  o[0] = (half_t)((v0.x - mu) * rs * gam[c0 + 0] + bet[c0 + 0]);
  o[1] = (half_t)((v0.y - mu) * rs * gam[c0 + 1] + bet[c0 + 1]);
  o[2] = (half_t)((v0.z - mu) * rs * gam[c0 + 2] + bet[c0 + 2]);
  o[3] = (half_t)((v0.w - mu) * rs * gam[c0 + 3] + bet[c0 + 3]);
  ((f16x4*)orow)[tid] = o;
  o[0] = (half_t)((v1.x - mu) * rs * gam[c1 + 0] + bet[c1 + 0]);
  o[1] = (half_t)((v1.y - mu) * rs * gam[c1 + 1] + bet[c1 + 1]);
  o[2] = (half_t)((v1.z - mu) * rs * gam[c1 + 2] + bet[c1 + 2]);
  o[3] = (half_t)((v1.w - mu) * rs * gam[c1 + 3] + bet[c1 + 3]);
  ((f16x4*)orow)[tid + 256] = o;
}

// ---------- host launch ----------
extern "C" void kernel_launch(void* const* d_in, const int* in_sizes, int n_in,
                              void* d_out, int out_size, void* d_ws, size_t ws_size,
                              hipStream_t stream) {
  const float* x       = (const float*)d_in[0];
  const float* W_left  = (const float*)d_in[1];
  const float* conv_w  = (const float*)d_in[2];
  const float* conv_b  = (const float*)d_in[3];
  const float* W_delta = (const float*)d_in[4];
  const float* b_delta = (const float*)d_in[5];
  const float* W_B     = (const float*)d_in[6];
  const float* W_C     = (const float*)d_in[7];
  const float* A_log   = (const float*)d_in[8];
  const float* W_right = (const float*)d_in[9];
  const float* ln_g    = (const float*)d_in[10];
  const float* ln_b    = (const float*)d_in[11];
  const float* W_out   = (const float*)d_in[12];

  float* buf = nullptr;
  hipGetSymbolAddress((void**)&buf, HIP_SYMBOL(g_buf));
  half_t* xh   = (half_t*)(buf + 0);
  half_t* wlh  = (half_t*)(buf + 4194304);
  half_t* wrh  = (half_t*)(buf + 5242880);
  half_t* wdh  = (half_t*)(buf + 6291456);
  half_t* wdl  = (half_t*)(buf + 8388608);
  half_t* woh  = (half_t*)(buf + 10485760);
  float* left  = buf + 11534336;
  float* xc    = buf + 28311552;
  half_t* xch  = (half_t*)(buf + 45088768);
  float* dlt   = buf + 61865984;
  float* gate  = buf + 78643200;
  float* yv    = buf + 95420416;
  half_t* nrmh = (half_t*)(buf + 112197632);
  float* bc    = buf + 120586240;
  half_t* wbch = (half_t*)(buf + 120848384);

  // fp32 -> fp16 staging
  f2h_k<<<8192, 256, 0, stream>>>(x, xh, TOK * DM / 4);
  f2h_k<<<2048, 256, 0, stream>>>(W_left, wlh, DI * DM / 4);
  f2h_k<<<2048, 256, 0, stream>>>(W_right, wrh, DI * DM / 4);
  f2h_k<<<2048, 256, 0, stream>>>(W_out, woh, DM * DI / 4);
  f2h2_k<<<4096, 256, 0, stream>>>(W_delta, wdh, wdl, DI * DI / 4);
  f2h_k<<<32, 256, 0, stream>>>(W_B, wbch, NS * DI / 4);
  f2h_k<<<32, 256, 0, stream>>>(W_C, wbch + NS * DI, NS * DI / 4);

  // left = x @ W_left^T
  gemm_mfma<0><<<dim3(DI / 128, TOK / 128), 256, 0, stream>>>(xh, wlh, nullptr, left, TOK, DI, DM);
  // xc = silu(causal_conv(left))  (fp32 + fp16)
  conv_silu_k<<<TOK * DI / 256, 256, 0, stream>>>(left, conv_w, conv_b, xc, xch);
  // gate = silu(x @ W_right^T)
  gemm_mfma<1><<<dim3(DI / 128, TOK / 128), 256, 0, stream>>>(xh, wrh, nullptr, gate, TOK, DI, DM);
  // delta = clip(softplus(xc @ W_delta^T + b_delta))  [2-term split fp16]
  gemm_mfma_split<<<dim3(DI / 128, TOK / 128), 256, 0, stream>>>(xch, wdh, wdl, b_delta, dlt, TOK, DI, DI);
  // B/C projections via MFMA (interleaved output)
  bc_mfma<<<TOK / 128, 256, 0, stream>>>(xch, wbch, bc);
  // selective scan with fused gate (DPP reduce + prefetch pipeline)
  scan_k<<<512, 256, 0, stream>>>(dlt, xc, gate, bc, A_log, yv);
  // layernorm -> fp16
  ln_k<<<TOK, 256, 0, stream>>>(yv, ln_g, ln_b, nrmh);
  // out = nrm @ W_out^T  (fp32 store to d_out)
  gemm_mfma<0><<<dim3(DM / 128, TOK / 128), 256, 0, stream>>>(nrmh, woh, nullptr, (float*)d_out, TOK, DM, DI);
}

// Round 9
// 927.765 us; speedup vs baseline: 3.5871x; 1.0676x over previous
//
#include <hip/hip_runtime.h>
#include <cstddef>

#define LL 2048
#define TOK 8192   // B*L = 4*2048
#define DM 1024
#define DI 2048
#define NS 16

typedef _Float16 half_t;
typedef __attribute__((ext_vector_type(8))) _Float16 f16x8;
typedef __attribute__((ext_vector_type(4))) _Float16 f16x4;
typedef __attribute__((ext_vector_type(4))) float f32x4;

// ---------- helpers ----------
__device__ __forceinline__ float softplus_f(float x) {
  return fmaxf(x, 0.f) + log1pf(__expf(-fabsf(x)));
}
__device__ __forceinline__ float silu_f(float x) {
  return x / (1.f + __expf(-x));
}
__device__ __forceinline__ void gload_lds16(const void* g, void* l) {
  __builtin_amdgcn_global_load_lds((const __attribute__((address_space(1))) void*)g,
                                   (__attribute__((address_space(3))) void*)l, 16, 0, 0);
}
// DPP row_shr add: after ctrl 0x111,0x112,0x114,0x118 lane15 of each row16 holds the row sum
#define DPP_ADD(v, ctrl) \
  ((v) + __int_as_float(__builtin_amdgcn_update_dpp(0, __float_as_int(v), (ctrl), 0xf, 0xf, true)))

// ---------- static scratch (float units) ----------
//  xh    @ 0            (4,194,304)   x as fp16
//  wlh   @ 4,194,304    (1,048,576)   W_left fp16   } contiguous = [W_left;W_right]
//  wrh   @ 5,242,880    (1,048,576)   W_right fp16  } as one [4096][1024]
//  wdh   @ 6,291,456    (2,097,152)   W_delta hi
//  wdl   @ 8,388,608    (2,097,152)   W_delta lo
//  woh   @ 10,485,760   (1,048,576)
//  left  @ 11,534,336   (16,777,216)
//  xc    @ 28,311,552   (16,777,216)
//  xch   @ 45,088,768   (8,388,608)   xc hi fp16
//  dlt   @ 61,865,984   (16,777,216)
//  gate  @ 78,643,200   (16,777,216)
//  y     @ 95,420,416   (16,777,216)
//  nrmh  @ 112,197,632  (8,388,608)   LN out fp16
//  bc    @ 120,586,240  (262,144)     packed: [row][2n]=B_n, [2n+1]=C_n
//  wbch  @ 120,848,384  (32,768)      [W_B;W_C] as fp16 [32][2048]
__device__ float g_buf[120881152];

// ---------- fp32 -> fp16 staging ----------
__global__ __launch_bounds__(256) void f2h_k(const float* __restrict__ in,
                                             half_t* __restrict__ out, int n4) {
  const int i = blockIdx.x * 256 + threadIdx.x;
  if (i >= n4) return;
  const float4 v = ((const float4*)in)[i];
  f16x4 o;
  o[0] = (half_t)v.x; o[1] = (half_t)v.y; o[2] = (half_t)v.z; o[3] = (half_t)v.w;
  ((f16x4*)out)[i] = o;
}

// ---------- fp32 -> (hi, lo) fp16 split staging ----------
__global__ __launch_bounds__(256) void f2h2_k(const float* __restrict__ in,
                                              half_t* __restrict__ hi,
                                              half_t* __restrict__ lo, int n4) {
  const int i = blockIdx.x * 256 + threadIdx.x;
  if (i >= n4) return;
  const float4 v = ((const float4*)in)[i];
  f16x4 h, l;
  h[0] = (half_t)v.x; h[1] = (half_t)v.y; h[2] = (half_t)v.z; h[3] = (half_t)v.w;
  l[0] = (half_t)(v.x - (float)h[0]);
  l[1] = (half_t)(v.y - (float)h[1]);
  l[2] = (half_t)(v.z - (float)h[2]);
  l[3] = (half_t)(v.w - (float)h[3]);
  ((f16x4*)hi)[i] = h;
  ((f16x4*)lo)[i] = l;
}

// ---------- fp16 MFMA GEMM: C[M,N] = act(A[M,K] @ W[N,K]^T + bias), fp32 out --
template <int ACT>   // 0 none, 1 silu
__global__ __launch_bounds__(256) void gemm_mfma(const half_t* __restrict__ A,
                                                 const half_t* __restrict__ W,
                                                 const float* __restrict__ bias,
                                                 float* __restrict__ C,
                                                 int M, int N, int K) {
  __shared__ half_t lA[4096];   // 8 KB
  __shared__ half_t lB[4096];   // 8 KB
  const int tid = threadIdx.x;
  const int bm0 = blockIdx.y * 128, bn0 = blockIdx.x * 128;
  const int lane = tid & 63, wave = tid >> 6;
  const int q = lane >> 4, mr = lane & 15;
  const int wm = (wave >> 1) * 64, wn = (wave & 1) * 64;
  const int flat0 = tid, flat1 = tid + 256;
  const int kc0 = flat0 >> 7, r0 = flat0 & 127;
  const int kc1 = flat1 >> 7, r1 = flat1 & 127;

  f32x4 acc[4][4];
#pragma unroll
  for (int i = 0; i < 4; ++i)
#pragma unroll
    for (int j = 0; j < 4; ++j) acc[i][j] = (f32x4){0.f, 0.f, 0.f, 0.f};

  for (int k0 = 0; k0 < K; k0 += 32) {
    gload_lds16(A + (size_t)(bm0 + r0) * K + k0 + kc0 * 8, lA + (size_t)flat0 * 8);
    gload_lds16(A + (size_t)(bm0 + r1) * K + k0 + kc1 * 8, lA + (size_t)flat1 * 8);
    gload_lds16(W + (size_t)(bn0 + r0) * K + k0 + kc0 * 8, lB + (size_t)flat0 * 8);
    gload_lds16(W + (size_t)(bn0 + r1) * K + k0 + kc1 * 8, lB + (size_t)flat1 * 8);
    __syncthreads();
    f16x8 af[4], bg[4];
#pragma unroll
    for (int t = 0; t < 4; ++t) {
      af[t] = *(const f16x8*)(lA + ((q << 10) + ((wm + t * 16 + mr) << 3)));
      bg[t] = *(const f16x8*)(lB + ((q << 10) + ((wn + t * 16 + mr) << 3)));
    }
#pragma unroll
    for (int i = 0; i < 4; ++i)
#pragma unroll
      for (int j = 0; j < 4; ++j)
        acc[i][j] = __builtin_amdgcn_mfma_f32_16x16x32_f16(af[i], bg[j], acc[i][j], 0, 0, 0);
    __syncthreads();
  }

#pragma unroll
  for (int i = 0; i < 4; ++i) {
#pragma unroll
    for (int j = 0; j < 4; ++j) {
      const int col = bn0 + wn + j * 16 + mr;
      const float bv = bias ? bias[col] : 0.f;
#pragma unroll
      for (int r = 0; r < 4; ++r) {
        const int row = bm0 + wm + i * 16 + q * 4 + r;
        float v = acc[i][j][r] + bv;
        if (ACT == 1) v = silu_f(v);
        C[(size_t)row * N + col] = v;
      }
    }
  }
}

// ---------- fused left+gate GEMM: W = [W_left;W_right] (4096 x 1024) ----------
// cols < DI -> left (no act); cols >= DI -> gate (silu). Tile is 128-wide and
// DI % 128 == 0, so the branch is block-uniform.
__global__ __launch_bounds__(256) void gemm_mfma_lg(const half_t* __restrict__ A,
                                                    const half_t* __restrict__ W,
                                                    float* __restrict__ left,
                                                    float* __restrict__ gate) {
  __shared__ half_t lA[4096];
  __shared__ half_t lB[4096];
  const int tid = threadIdx.x;
  const int bm0 = blockIdx.y * 128, bn0 = blockIdx.x * 128;
  const int K = DM;
  const int lane = tid & 63, wave = tid >> 6;
  const int q = lane >> 4, mr = lane & 15;
  const int wm = (wave >> 1) * 64, wn = (wave & 1) * 64;
  const int flat1 = tid + 256;
  const int kc0 = tid >> 7, r0 = tid & 127;
  const int kc1 = flat1 >> 7, r1 = flat1 & 127;

  f32x4 acc[4][4];
#pragma unroll
  for (int i = 0; i < 4; ++i)
#pragma unroll
    for (int j = 0; j < 4; ++j) acc[i][j] = (f32x4){0.f, 0.f, 0.f, 0.f};

  for (int k0 = 0; k0 < K; k0 += 32) {
    gload_lds16(A + (size_t)(bm0 + r0) * K + k0 + kc0 * 8, lA + (size_t)tid * 8);
    gload_lds16(A + (size_t)(bm0 + r1) * K + k0 + kc1 * 8, lA + (size_t)flat1 * 8);
    gload_lds16(W + (size_t)(bn0 + r0) * K + k0 + kc0 * 8, lB + (size_t)tid * 8);
    gload_lds16(W + (size_t)(bn0 + r1) * K + k0 + kc1 * 8, lB + (size_t)flat1 * 8);
    __syncthreads();
    f16x8 af[4], bg[4];
#pragma unroll
    for (int t = 0; t < 4; ++t) {
      af[t] = *(const f16x8*)(lA + ((q << 10) + ((wm + t * 16 + mr) << 3)));
      bg[t] = *(const f16x8*)(lB + ((q << 10) + ((wn + t * 16 + mr) << 3)));
    }
#pragma unroll
    for (int i = 0; i < 4; ++i)
#pragma unroll
      for (int j = 0; j < 4; ++j)
        acc[i][j] = __builtin_amdgcn_mfma_f32_16x16x32_f16(af[i], bg[j], acc[i][j], 0, 0, 0);
    __syncthreads();
  }

  const int is_gate = (bn0 >= DI);
  float* out = is_gate ? gate : left;
  const int cb = bn0 - (is_gate ? DI : 0);
#pragma unroll
  for (int i = 0; i < 4; ++i) {
#pragma unroll
    for (int j = 0; j < 4; ++j) {
      const int col = cb + wn + j * 16 + mr;
#pragma unroll
      for (int r = 0; r < 4; ++r) {
        const int row = bm0 + wm + i * 16 + q * 4 + r;
        float v = acc[i][j][r];
        if (is_gate) v = silu_f(v);
        out[(size_t)row * DI + col] = v;
      }
    }
  }
}

// ---------- 2-term split GEMM, 256x128 tile, 512 threads (8 waves) ----------
// acc += Ah*Wh + Ah*Wl.  Staged bytes per MFMA cut 33% vs 128-tile; grid 512
// blocks = 2/CU fully co-resident.
__global__ __launch_bounds__(512, 4) void gemm_mfma_split(const half_t* __restrict__ Ah,
                                                          const half_t* __restrict__ Wh,
                                                          const half_t* __restrict__ Wl,
                                                          const float* __restrict__ bias,
                                                          float* __restrict__ C,
                                                          int M, int N, int K) {
  __shared__ half_t lAh[8192];            // [kc4][256][8]  16 KB
  __shared__ half_t lBh[4096], lBl[4096]; // [kc4][128][8]  8 KB each
  const int tid = threadIdx.x;
  const int bm0 = blockIdx.y * 256, bn0 = blockIdx.x * 128;
  const int lane = tid & 63, wave = tid >> 6;
  const int q = lane >> 4, mr = lane & 15;
  const int wm = (wave >> 1) * 64, wn = (wave & 1) * 64;
  // A staging: 1024 chunks, 2 per thread
  const int aflat1 = tid + 512;
  const int akc0 = tid >> 8, ar0 = tid & 255;
  const int akc1 = aflat1 >> 8, ar1 = aflat1 & 255;
  // W staging: 512 chunks, 1 per thread (both Wh and Wl)
  const int wkc = tid >> 7, wr = tid & 127;

  f32x4 acc[4][4];
#pragma unroll
  for (int i = 0; i < 4; ++i)
#pragma unroll
    for (int j = 0; j < 4; ++j) acc[i][j] = (f32x4){0.f, 0.f, 0.f, 0.f};

  for (int k0 = 0; k0 < K; k0 += 32) {
    gload_lds16(Ah + (size_t)(bm0 + ar0) * K + k0 + akc0 * 8, lAh + (size_t)tid * 8);
    gload_lds16(Ah + (size_t)(bm0 + ar1) * K + k0 + akc1 * 8, lAh + (size_t)aflat1 * 8);
    gload_lds16(Wh + (size_t)(bn0 + wr) * K + k0 + wkc * 8, lBh + (size_t)tid * 8);
    gload_lds16(Wl + (size_t)(bn0 + wr) * K + k0 + wkc * 8, lBl + (size_t)tid * 8);
    __syncthreads();
    f16x8 ah[4], bh[4], bl[4];
#pragma unroll
    for (int t = 0; t < 4; ++t) {
      const int ao = (q << 11) + ((wm + t * 16 + mr) << 3);   // q*256*8
      const int bo = (q << 10) + ((wn + t * 16 + mr) << 3);   // q*128*8
      ah[t] = *(const f16x8*)(lAh + ao);
      bh[t] = *(const f16x8*)(lBh + bo);
      bl[t] = *(const f16x8*)(lBl + bo);
    }
#pragma unroll
    for (int i = 0; i < 4; ++i)
#pragma unroll
      for (int j = 0; j < 4; ++j) {
        acc[i][j] = __builtin_amdgcn_mfma_f32_16x16x32_f16(ah[i], bh[j], acc[i][j], 0, 0, 0);
        acc[i][j] = __builtin_amdgcn_mfma_f32_16x16x32_f16(ah[i], bl[j], acc[i][j], 0, 0, 0);
      }
    __syncthreads();
  }

  const int wmg = (wave >> 1) * 64;   // 0,64,128,192 across 256 rows
#pragma unroll
  for (int i = 0; i < 4; ++i) {
#pragma unroll
    for (int j = 0; j < 4; ++j) {
      const int col = bn0 + wn + j * 16 + mr;
      const float bv = bias[col];
#pragma unroll
      for (int r = 0; r < 4; ++r) {
        const int row = bm0 + wmg + i * 16 + q * 4 + r;
        float v = softplus_f(acc[i][j][r] + bv);
        v = fminf(fmaxf(v, 1e-4f), 10.f);
        C[(size_t)row * N + col] = v;
      }
    }
  }
}

// ---------- skinny MFMA GEMM for B/C: bc[M,32] = xch @ [W_B;W_C]^T ----------
__global__ __launch_bounds__(256) void bc_mfma(const half_t* __restrict__ A,
                                               const half_t* __restrict__ Wbc,
                                               float* __restrict__ bc) {
  __shared__ half_t lA[4096];   // [kc4][128][8]  8 KB
  __shared__ half_t lB[1024];   // [kc4][32][8]   2 KB
  const int tid = threadIdx.x;
  const int bm0 = blockIdx.x * 128;
  const int lane = tid & 63, wave = tid >> 6;
  const int q = lane >> 4, mr = lane & 15;
  const int wm = wave * 32;
  const int flat1 = tid + 256;
  const int kcA0 = tid >> 7, rA0 = tid & 127;
  const int kcA1 = flat1 >> 7, rA1 = flat1 & 127;
  const int kcB = tid >> 5, rB = tid & 31;   // threads 0..127

  f32x4 acc[2][2];
#pragma unroll
  for (int i = 0; i < 2; ++i)
#pragma unroll
    for (int j = 0; j < 2; ++j) acc[i][j] = (f32x4){0.f, 0.f, 0.f, 0.f};

  for (int k0 = 0; k0 < DI; k0 += 32) {
    gload_lds16(A + (size_t)(bm0 + rA0) * DI + k0 + kcA0 * 8, lA + (size_t)tid * 8);
    gload_lds16(A + (size_t)(bm0 + rA1) * DI + k0 + kcA1 * 8, lA + (size_t)flat1 * 8);
    if (tid < 128)
      gload_lds16(Wbc + (size_t)rB * DI + k0 + kcB * 8, lB + (size_t)tid * 8);
    __syncthreads();
    f16x8 af[2], bg[2];
#pragma unroll
    for (int t = 0; t < 2; ++t) {
      af[t] = *(const f16x8*)(lA + ((q << 10) + ((wm + t * 16 + mr) << 3)));
      bg[t] = *(const f16x8*)(lB + ((q << 8) + ((t * 16 + mr) << 3)));
    }
#pragma unroll
    for (int i = 0; i < 2; ++i)
#pragma unroll
      for (int j = 0; j < 2; ++j)
        acc[i][j] = __builtin_amdgcn_mfma_f32_16x16x32_f16(af[i], bg[j], acc[i][j], 0, 0, 0);
    __syncthreads();
  }

#pragma unroll
  for (int i = 0; i < 2; ++i) {
#pragma unroll
    for (int j = 0; j < 2; ++j) {
#pragma unroll
      for (int r = 0; r < 4; ++r) {
        const int row = bm0 + wm + i * 16 + q * 4 + r;
        bc[(size_t)row * 32 + 2 * mr + j] = acc[i][j][r];
      }
    }
  }
}

// ---------- causal depthwise conv(4) + bias + silu (fp32 + fp16 out) ----------
__global__ __launch_bounds__(256) void conv_silu_k(const float* __restrict__ left,
                                                   const float* __restrict__ cw,
                                                   const float* __restrict__ cb,
                                                   float* __restrict__ xc,
                                                   half_t* __restrict__ xch) {
  const int idx = blockIdx.x * 256 + threadIdx.x;  // over TOK*DI
  const int d = idx & (DI - 1);
  const int bt = idx >> 11;
  const int t = bt & (LL - 1);
  const float4 wv = *(const float4*)(cw + (size_t)d * 4);
  float acc = cb[d];
  const size_t base = (size_t)idx;
  if (t >= 3) {
    acc += left[base - 3 * DI] * wv.x + left[base - 2 * DI] * wv.y +
           left[base - DI] * wv.z + left[base] * wv.w;
  } else {
    acc += left[base] * wv.w;
    if (t >= 1) acc += left[base - DI] * wv.z;
    if (t >= 2) acc += left[base - 2 * DI] * wv.y;
  }
  const float v = silu_f(acc);
  xc[base] = v;
  xch[base] = (half_t)v;
}

// ---------- selective scan: DPP reduce, packed LDS, prefetch pipeline ----------
#define ST 32
__global__ __launch_bounds__(256) void scan_k(const float* __restrict__ delta,
                                              const float* __restrict__ xc,
                                              const float* __restrict__ gate,
                                              const float* __restrict__ bcp,
                                              const float* __restrict__ A_log,
                                              float* __restrict__ y) {
  __shared__ float dx2[16 * 68];
  __shared__ float bcs[ST * 32];
  __shared__ float ys[ST * 16];
  const int tid = threadIdx.x;
  const int b  = blockIdx.x >> 7;
  const int d0 = (blockIdx.x & 127) << 4;
  const int n  = tid & 15;
  const int ch = tid >> 4;
  const float An = -softplus_f(A_log[n]);

  const int t_a = tid >> 4, c_a = tid & 15;
  const int t_b = t_a + 16;

  float h = 0.f;
  const size_t batch_base = (size_t)b * LL * DI + d0;
  const size_t batch_bc   = (size_t)b * LL * 32;

  size_t rb_cur = batch_base;
  float g0, g1;
  {
    const size_t ra = rb_cur + (size_t)t_a * DI + c_a;
    const size_t rbx = rb_cur + (size_t)t_b * DI + c_a;
    const float d0v = delta[ra], x0v = xc[ra];
    const float d1v = delta[rbx], x1v = xc[rbx];
    g0 = gate[ra]; g1 = gate[rbx];
    const float2 b0 = *(const float2*)&bcp[batch_bc + (size_t)t_a * 32 + 2 * c_a];
    const float2 b1 = *(const float2*)&bcp[batch_bc + (size_t)t_b * 32 + 2 * c_a];
    *(float2*)&dx2[c_a * 68 + t_a * 2] = make_float2(d0v, x0v);
    *(float2*)&dx2[c_a * 68 + t_b * 2] = make_float2(d1v, x1v);
    *(float2*)&bcs[t_a * 32 + 2 * c_a] = b0;
    *(float2*)&bcs[t_b * 32 + 2 * c_a] = b1;
  }
  __syncthreads();

  for (int it = 0; it < LL / ST; ++it) {
    float nd0, nx0, ng0, nd1, nx1, ng1;
    float2 nb0, nb1;
    const size_t rb_nxt = batch_base + (size_t)(it + 1) * ST * DI;
    if (it + 1 < LL / ST) {
      const size_t ra = rb_nxt + (size_t)t_a * DI + c_a;
      const size_t rbx = rb_nxt + (size_t)t_b * DI + c_a;
      nd0 = delta[ra]; nx0 = xc[ra]; ng0 = gate[ra];
      nd1 = delta[rbx]; nx1 = xc[rbx]; ng1 = gate[rbx];
      const size_t bcb = batch_bc + (size_t)(it + 1) * ST * 32;
      nb0 = *(const float2*)&bcp[bcb + (size_t)t_a * 32 + 2 * c_a];
      nb1 = *(const float2*)&bcp[bcb + (size_t)t_b * 32 + 2 * c_a];
    }

    const float* dxp = &dx2[ch * 68];
#pragma unroll
    for (int tt = 0; tt < ST; tt += 2) {
      const float4 v = *(const float4*)&dxp[tt * 2];
      const float2 bc0 = *(const float2*)&bcs[tt * 32 + 2 * n];
      const float2 bc1 = *(const float2*)&bcs[(tt + 1) * 32 + 2 * n];
      float ab = __expf(v.x * An);
      h = fmaf(ab, h, v.x * v.y * bc0.x);
      float p = h * bc0.y;
      p = DPP_ADD(p, 0x111); p = DPP_ADD(p, 0x112);
      p = DPP_ADD(p, 0x114); p = DPP_ADD(p, 0x118);
      if (n == 15) ys[tt * 16 + ch] = p;
      ab = __expf(v.z * An);
      h = fmaf(ab, h, v.z * v.w * bc1.x);
      p = h * bc1.y;
      p = DPP_ADD(p, 0x111); p = DPP_ADD(p, 0x112);
      p = DPP_ADD(p, 0x114); p = DPP_ADD(p, 0x118);
      if (n == 15) ys[(tt + 1) * 16 + ch] = p;
    }
    __syncthreads();

    if (it + 1 < LL / ST) {
      *(float2*)&dx2[c_a * 68 + t_a * 2] = make_float2(nd0, nx0);
      *(float2*)&dx2[c_a * 68 + t_b * 2] = make_float2(nd1, nx1);
      *(float2*)&bcs[t_a * 32 + 2 * c_a] = nb0;
      *(float2*)&bcs[t_b * 32 + 2 * c_a] = nb1;
    }
    y[rb_cur + (size_t)t_a * DI + c_a] = ys[t_a * 16 + c_a] * g0;
    y[rb_cur + (size_t)t_b * DI + c_a] = ys[t_b * 16 + c_a] * g1;
    g0 = ng0; g1 = ng1;
    rb_cur = rb_nxt;
    __syncthreads();
  }
}

// ---------- layernorm over d_inner (fp16 out for MFMA consumer) ----------
__global__ __launch_bounds__(256) void ln_k(const float* __restrict__ y,
                                            const float* __restrict__ gam,
                                            const float* __restrict__ bet,
                                            half_t* __restrict__ outn) {
  const int row = blockIdx.x;
  const int tid = threadIdx.x;
  const float* yr = y + (size_t)row * DI;
  const float4 v0 = ((const float4*)yr)[tid];
  const float4 v1 = ((const float4*)yr)[tid + 256];
  float s = v0.x + v0.y + v0.z + v0.w + v1.x + v1.y + v1.z + v1.w;
  float q = v0.x * v0.x + v0.y * v0.y + v0.z * v0.z + v0.w * v0.w +
            v1.x * v1.x + v1.y * v1.y + v1.z * v1.z + v1.w * v1.w;
  for (int off = 32; off > 0; off >>= 1) {
    s += __shfl_down(s, off);
    q += __shfl_down(q, off);
  }
  __shared__ float sred[4], qred[4];
  const int wid = tid >> 6;
  if ((tid & 63) == 0) { sred[wid] = s; qred[wid] = q; }
  __syncthreads();
  s = sred[0] + sred[1] + sred[2] + sred[3];
  q = qred[0] + qred[1] + qred[2] + qred[3];
  const float mu = s * (1.f / DI);
  const float rs = rsqrtf(q * (1.f / DI) - mu * mu + 1e-5f);
  half_t* orow = outn + (size_t)row * DI;
  const int c0 = tid * 4, c1 = (tid + 256) * 4;
  f16x4 o;
  o[0] = (half_t)((v0.x - mu) * rs * gam[c0 + 0] + bet[c0 + 0]);
  o[1] = (half_t)((v0.y - mu) * rs * gam[c0 + 1] + bet[c0 + 1]);
  o[2] = (half_t)((v0.z - mu) * rs * gam[c0 + 2] + bet[c0 + 2]);
  o[3] = (half_t)((v0.w - mu) * rs * gam[c0 + 3] + bet[c0 + 3]);
  ((f16x4*)orow)[tid] = o;
  o[0] = (half_t)((v1.x - mu) * rs * gam[c1 + 0] + bet[c1 + 0]);
  o[1] = (half_t)((v1.y - mu) * rs * gam[c1 + 1] + bet[c1 + 1]);
  o[2] = (half_t)((v1.z - mu) * rs * gam[c1 + 2] + bet[c1 + 2]);
  o[3] = (half_t)((v1.w - mu) * rs * gam[c1 + 3] + bet[c1 + 3]);
  ((f16x4*)orow)[tid + 256] = o;
}

// ---------- host launch ----------
extern "C" void kernel_launch(void* const* d_in, const int* in_sizes, int n_in,
                              void* d_out, int out_size, void* d_ws, size_t ws_size,
                              hipStream_t stream) {
  const float* x       = (const float*)d_in[0];
  const float* W_left  = (const float*)d_in[1];
  const float* conv_w  = (const float*)d_in[2];
  const float* conv_b  = (const float*)d_in[3];
  const float* W_delta = (const float*)d_in[4];
  const float* b_delta = (const float*)d_in[5];
  const float* W_B     = (const float*)d_in[6];
  const float* W_C     = (const float*)d_in[7];
  const float* A_log   = (const float*)d_in[8];
  const float* W_right = (const float*)d_in[9];
  const float* ln_g    = (const float*)d_in[10];
  const float* ln_b    = (const float*)d_in[11];
  const float* W_out   = (const float*)d_in[12];

  float* buf = nullptr;
  hipGetSymbolAddress((void**)&buf, HIP_SYMBOL(g_buf));
  half_t* xh   = (half_t*)(buf + 0);
  half_t* wlgh = (half_t*)(buf + 4194304);   // [W_left;W_right] 4096x1024 fp16
  half_t* wrh  = (half_t*)(buf + 5242880);
  half_t* wdh  = (half_t*)(buf + 6291456);
  half_t* wdl  = (half_t*)(buf + 8388608);
  half_t* woh  = (half_t*)(buf + 10485760);
  float* left  = buf + 11534336;
  float* xc    = buf + 28311552;
  half_t* xch  = (half_t*)(buf + 45088768);
  float* dlt   = buf + 61865984;
  float* gate  = buf + 78643200;
  float* yv    = buf + 95420416;
  half_t* nrmh = (half_t*)(buf + 112197632);
  float* bc    = buf + 120586240;
  half_t* wbch = (half_t*)(buf + 120848384);

  // fp32 -> fp16 staging
  f2h_k<<<8192, 256, 0, stream>>>(x, xh, TOK * DM / 4);
  f2h_k<<<2048, 256, 0, stream>>>(W_left, wlgh, DI * DM / 4);
  f2h_k<<<2048, 256, 0, stream>>>(W_right, wrh, DI * DM / 4);
  f2h_k<<<2048, 256, 0, stream>>>(W_out, woh, DM * DI / 4);
  f2h2_k<<<4096, 256, 0, stream>>>(W_delta, wdh, wdl, DI * DI / 4);
  f2h_k<<<32, 256, 0, stream>>>(W_B, wbch, NS * DI / 4);
  f2h_k<<<32, 256, 0, stream>>>(W_C, wbch + NS * DI, NS * DI / 4);

  // left = x @ W_left^T ; gate = silu(x @ W_right^T)  -- fused, N=4096
  gemm_mfma_lg<<<dim3(2 * DI / 128, TOK / 128), 256, 0, stream>>>(xh, wlgh, left, gate);
  // xc = silu(causal_conv(left))  (fp32 + fp16)
  conv_silu_k<<<TOK * DI / 256, 256, 0, stream>>>(left, conv_w, conv_b, xc, xch);
  // delta = clip(softplus(xc @ W_delta^T + b_delta))  [2-term split, 256x128 tile]
  gemm_mfma_split<<<dim3(DI / 128, TOK / 256), 512, 0, stream>>>(xch, wdh, wdl, b_delta, dlt, TOK, DI, DI);
  // B/C projections via MFMA (interleaved output)
  bc_mfma<<<TOK / 128, 256, 0, stream>>>(xch, wbch, bc);
  // selective scan with fused gate (DPP reduce + prefetch pipeline)
  scan_k<<<512, 256, 0, stream>>>(dlt, xc, gate, bc, A_log, yv);
  // layernorm -> fp16
  ln_k<<<TOK, 256, 0, stream>>>(yv, ln_g, ln_b, nrmh);
  // out = nrm @ W_out^T  (fp32 store to d_out)
  gemm_mfma<0><<<dim3(DM / 128, TOK / 128), 256, 0, stream>>>(nrmh, woh, nullptr, (float*)d_out, TOK, DM, DI);
}